// Round 3
// baseline (713.907 us; speedup 1.0000x reference)
//
#include <hip/hip_runtime.h>

#define N_NODES 50000
#define N_EDGES 1600000
#define N_GRAPHS 256
#define HID 128
#define OUT_CH 10
#define NBUCK 512    // dst buckets for two-phase build
#define BNODES ((N_NODES + NBUCK - 1) / NBUCK)  // 98 nodes per bucket
#define BCAP 6144    // slots per bucket region
#define P1BLK 250    // phase-1 blocks (EPB = 6400, divisible by 4)
#define EPB (N_EDGES / P1BLK)
#define DSENTINEL 127  // dloc sentinel for alignment-pad slots (valid dloc < 98)
#define NR 4           // src ranges for L2-windowed gather (order kept inside compacted rows)
#define RSTEP ((N_NODES + NR - 1) / NR)  // 12500 -> 3.2 MB feature window / range
#define PAD_T 96       // compacted ELL row capacity (max degree < 80 + pad headroom)
#define DEG_CAP 88     // clamp for safety (mult of 8, <= PAD_T)

typedef __bf16 bf16x8 __attribute__((ext_vector_type(8)));
typedef float f32x4 __attribute__((ext_vector_type(4)));

__device__ inline unsigned bf16rne(float f) {
    unsigned u = __float_as_uint(f);
    return (u + 0x7fffu + ((u >> 16) & 1u)) >> 16;
}

// cpair payload: .x = (dloc<<16) | src   (src < 65536, dloc < 98), .y = bitcast w
// ---------------- phase 1: bucket edges, line-aligned per-block reservations -------
__global__ __launch_bounds__(1024) void bucket_k(const int* __restrict__ src,
                                                 const int* __restrict__ dst,
                                                 const float* __restrict__ ew,
                                                 int* __restrict__ bcount,
                                                 int2* __restrict__ cpair) {
    __shared__ int hist[NBUCK];
    __shared__ int base[NBUCK];
    int t = threadIdx.x;
    for (int i = t; i < NBUCK; i += 1024) hist[i] = 0;
    __syncthreads();
    const int ch0 = blockIdx.x * (EPB / 4);
    const int ch1 = ch0 + (EPB / 4);
    const int4* dst4 = (const int4*)dst;
    for (int ci = ch0 + t; ci < ch1; ci += 1024) {
        int4 d4 = dst4[ci];
        atomicAdd(&hist[d4.x / BNODES], 1);
        atomicAdd(&hist[d4.y / BNODES], 1);
        atomicAdd(&hist[d4.z / BNODES], 1);
        atomicAdd(&hist[d4.w / BNODES], 1);
    }
    __syncthreads();
    for (int i = t; i < NBUCK; i += 1024) {
        int c = hist[i];
        base[i] = (c > 0) ? atomicAdd(&bcount[i], (c + 7) & ~7) : 0;
        hist[i] = 0;  // reuse as within-reservation cursor
    }
    __syncthreads();
    for (int ci = ch0 + t; ci < ch1; ci += 1024) {
        int4 d4 = dst4[ci];
        int e = ci * 4;
#define PROC(dd, ee)                                              \
        {                                                         \
            int b = (dd) / BNODES;                                \
            int off = base[b] + atomicAdd(&hist[b], 1);           \
            if (off < BCAP) {                                     \
                int2 p;                                           \
                p.x = (((dd) - b * BNODES) << 16) | src[ee];      \
                p.y = __float_as_int(ew[ee]);                     \
                cpair[b * BCAP + off] = p;                        \
            }                                                     \
        }
        PROC(d4.x, e)
        PROC(d4.y, e + 1)
        PROC(d4.z, e + 2)
        PROC(d4.w, e + 3)
#undef PROC
    }
    __syncthreads();
    for (int i = t; i < NBUCK; i += 1024) {
        int c = hist[i];
        int ac = (c + 7) & ~7;
        for (int j = c; j < ac; ++j) {
            int off = base[i] + j;
            if (off < BCAP) {
                int2 p;
                p.x = DSENTINEL << 16;
                p.y = 0;
                cpair[i * BCAP + off] = p;
            }
        }
    }
}

// ---------------- ELL count pass: counts/offsets, dinv, deg histogram, pads --------
__global__ __launch_bounds__(512) void ellcount_k(const int* __restrict__ bcount,
                                                  const int2* __restrict__ cpair,
                                                  int* __restrict__ loff,
                                                  int* __restrict__ fill,
                                                  float* __restrict__ dinv,
                                                  int* __restrict__ deghist,
                                                  int2* __restrict__ ell) {
    __shared__ int lfill[BNODES * NR];
    __shared__ float wsum[BNODES];
    int b = blockIdx.x;
    int t = threadIdx.x;
    for (int i = t; i < BNODES * NR; i += 512) lfill[i] = 0;
    for (int i = t; i < BNODES; i += 512) wsum[i] = 0.f;
    __syncthreads();
    int cnt = bcount[b];
    if (cnt > BCAP) cnt = BCAP;
    int n0 = b * BNODES;
    int sbase = b * BCAP;
    for (int i = t; i < cnt; i += 512) {
        int2 p = cpair[sbase + i];
        int dloc = p.x >> 16;
        if (dloc < BNODES) {
            int s = p.x & 0xffff;
            atomicAdd(&lfill[dloc * NR + s / RSTEP], 1);
            atomicAdd(&wsum[dloc], __int_as_float(p.y));
        }
    }
    __syncthreads();
    for (int i = t; i < BNODES; i += 512) {
        int n = n0 + i;
        if (n >= N_NODES) continue;
        int c0 = lfill[i * NR + 0], c1 = lfill[i * NR + 1];
        int c2 = lfill[i * NR + 2], c3 = lfill[i * NR + 3];
        int ct = c0 + c1 + c2 + c3;
        if (ct > DEG_CAP) ct = DEG_CAP;
        int* lo = loff + ((size_t)b * BNODES + i) * NR;
        lo[0] = 0; lo[1] = c0; lo[2] = c0 + c1; lo[3] = c0 + c1 + c2;
        fill[n] = ct;
        dinv[n] = rsqrtf(wsum[i] + 1.0f);
        atomicAdd(&deghist[ct], 1);
        int cp = (ct + 7) & ~7;  // zero-pad to mult-8: pad entries contribute 0
        int2 z; z.x = 0; z.y = 0;
        for (int j = ct; j < cp; ++j) ell[(size_t)n * PAD_T + j] = z;
    }
}

// ---------------- ELL fill pass: compacted scatter with premultiplied weights ------
__global__ __launch_bounds__(512) void ellfill_k(const int* __restrict__ bcount,
                                                 const int2* __restrict__ cpair,
                                                 const int* __restrict__ loff,
                                                 const float* __restrict__ dinv,
                                                 int2* __restrict__ ell) {
    __shared__ int lcur[BNODES * NR];
    int b = blockIdx.x;
    int t = threadIdx.x;
    for (int i = t; i < BNODES * NR; i += 512)
        lcur[i] = loff[(size_t)b * BNODES * NR + i];
    __syncthreads();
    int cnt = bcount[b];
    if (cnt > BCAP) cnt = BCAP;
    int n0 = b * BNODES;
    int sbase = b * BCAP;
    for (int i = t; i < cnt; i += 512) {
        int2 p = cpair[sbase + i];
        int dloc = p.x >> 16;
        if (dloc < BNODES) {
            int s = p.x & 0xffff;
            int r = s / RSTEP;
            int pos = atomicAdd(&lcur[dloc * NR + r], 1);
            if (pos < DEG_CAP) {
                int2 q;
                q.x = s;
                q.y = __float_as_int(__int_as_float(p.y) * dinv[s]);  // w * dinv[src]
                ell[(size_t)(n0 + dloc) * PAD_T + pos] = q;
            }
        }
    }
}

// ---------------- degree-bin prefix sum (counting-sort step 2) ---------------------
__global__ __launch_bounds__(128) void dprefix_k(const int* __restrict__ deghist,
                                                 int* __restrict__ bincur) {
    __shared__ int h[128];
    int t = threadIdx.x;
    h[t] = deghist[t];
    __syncthreads();
    if (t == 0) {
        int s = 0;
        for (int k = 0; k < 128; ++k) { int v = h[k]; h[k] = s; s += v; }
    }
    __syncthreads();
    bincur[t] = h[t];
}

// ---------------- fused prep: graph boundaries + W bf16 transpose ------------------
__global__ __launch_bounds__(256) void prep_k(const int* __restrict__ batch,
                                              int* __restrict__ gstart,
                                              const float* __restrict__ W1,
                                              const float* __restrict__ W2,
                                              const float* __restrict__ W3,
                                              unsigned short* __restrict__ Wt) {
    int idx = blockIdx.x * 256 + threadIdx.x;
    if (idx < 3 * 16384) {
        int m = idx >> 14;
        int r = idx & 16383;
        const float* W = (m == 0) ? W1 : (m == 1) ? W2 : W3;
        int c = r >> 7, k = r & 127;
        Wt[idx] = (unsigned short)bf16rne(W[k * 128 + c]);
    }
    if (idx < N_NODES) {
        int b = batch[idx];
        int bprev = (idx == 0) ? -1 : batch[idx - 1];
        for (int g = bprev + 1; g <= b; ++g) gstart[g] = idx;
        if (idx == N_NODES - 1) {
            for (int g = b + 1; g <= N_GRAPHS; ++g) gstart[g] = N_NODES;
        }
    }
}

// ------- one-time x fp32 -> bf16 convert + degree-sort scatter (LPT order) ---------
__global__ __launch_bounds__(256) void xconv_k(const float* __restrict__ x,
                                               unsigned short* __restrict__ xb,
                                               const int* __restrict__ fill,
                                               int* __restrict__ bincur,
                                               int* __restrict__ order) {
    int i = blockIdx.x * 256 + threadIdx.x;  // one thread per 8 channels
    if (i < N_NODES * 16) {
        const float4* p = (const float4*)x + (size_t)i * 2;
        float4 lo = p[0], hi = p[1];
        uint4 pk;
        pk.x = bf16rne(lo.x) | (bf16rne(lo.y) << 16);
        pk.y = bf16rne(lo.z) | (bf16rne(lo.w) << 16);
        pk.z = bf16rne(hi.x) | (bf16rne(hi.y) << 16);
        pk.w = bf16rne(hi.z) | (bf16rne(hi.w) << 16);
        ((uint4*)xb)[i] = pk;
    }
    if (i < N_NODES) {
        int d = fill[i];
        int pos = atomicAdd(&bincur[d], 1);
        order[N_NODES - 1 - pos] = i;  // descending degree: heavy blocks first (LPT)
    }
}

// ---------------- fused layer: out = relu( agg(x) @ W + b ) ------------------------
// Blocks process 16 equal-degree nodes (order[]): phase-A/B barrier is cheap, lane
// groups convergent. Compacted zero-padded ELL rows (mult-8), premultiplied weights,
// 8 feature loads in flight.
__global__ __launch_bounds__(256, 8) void aggemm_k(const unsigned short* __restrict__ tb,
                                                   const int* __restrict__ order,
                                                   const int* __restrict__ fill,
                                                   const int2* __restrict__ ell,
                                                   const float* __restrict__ dinv,
                                                   const unsigned short* __restrict__ Wt,
                                                   const float* __restrict__ bias,
                                                   unsigned short* __restrict__ outB,
                                                   int relu) {
    __shared__ unsigned short tile[16][136];  // 272 B row stride: 4-bank row shift
    __shared__ int onode[16];
    int lane16 = threadIdx.x & 15;
    int local = threadIdx.x >> 4;
    int n = order[blockIdx.x * 16 + local];  // 3125*16 == N_NODES exactly
    if (lane16 == 0) onode[local] = n;
    float dn = dinv[n];
    int c = fill[n];
    const uint4* tb4 = (const uint4*)tb;  // feature row = 16 uint4
#define UNP(q, f)                                                 \
    float f##0 = __uint_as_float((q).x << 16);                    \
    float f##1 = __uint_as_float((q).x & 0xffff0000u);            \
    float f##2 = __uint_as_float((q).y << 16);                    \
    float f##3 = __uint_as_float((q).y & 0xffff0000u);            \
    float f##4 = __uint_as_float((q).z << 16);                    \
    float f##5 = __uint_as_float((q).z & 0xffff0000u);            \
    float f##6 = __uint_as_float((q).w << 16);                    \
    float f##7 = __uint_as_float((q).w & 0xffff0000u);
    uint4 qs = tb4[(n << 4) + lane16];
    UNP(qs, S)
    float acc0 = S0 * dn, acc1 = S1 * dn, acc2 = S2 * dn, acc3 = S3 * dn;
    float acc4 = S4 * dn, acc5 = S5 * dn, acc6 = S6 * dn, acc7 = S7 * dn;
    const int4* ep4 = (const int4*)(ell + (size_t)n * PAD_T);  // 2 entries / int4
    int cr = (c + 7) & ~7;
#pragma unroll 1
    for (int i = 0; i < cr; i += 8) {
        int4 ee0 = ep4[(i >> 1) + 0];
        int4 ee1 = ep4[(i >> 1) + 1];
        int4 ee2 = ep4[(i >> 1) + 2];
        int4 ee3 = ep4[(i >> 1) + 3];
        uint4 q0 = tb4[(ee0.x << 4) + lane16];
        uint4 q1 = tb4[(ee0.z << 4) + lane16];
        uint4 q2 = tb4[(ee1.x << 4) + lane16];
        uint4 q3 = tb4[(ee1.z << 4) + lane16];
        uint4 q4 = tb4[(ee2.x << 4) + lane16];
        uint4 q5 = tb4[(ee2.z << 4) + lane16];
        uint4 q6 = tb4[(ee3.x << 4) + lane16];
        uint4 q7 = tb4[(ee3.z << 4) + lane16];
        float w0 = __int_as_float(ee0.y), w1 = __int_as_float(ee0.w);
        float w2 = __int_as_float(ee1.y), w3 = __int_as_float(ee1.w);
        float w4 = __int_as_float(ee2.y), w5 = __int_as_float(ee2.w);
        float w6 = __int_as_float(ee3.y), w7 = __int_as_float(ee3.w);
        UNP(q0, A)
        UNP(q1, B)
        UNP(q2, C)
        UNP(q3, D)
        UNP(q4, E)
        UNP(q5, F)
        UNP(q6, G)
        UNP(q7, H)
        acc0 += A0 * w0 + B0 * w1 + C0 * w2 + D0 * w3 + E0 * w4 + F0 * w5 + G0 * w6 + H0 * w7;
        acc1 += A1 * w0 + B1 * w1 + C1 * w2 + D1 * w3 + E1 * w4 + F1 * w5 + G1 * w6 + H1 * w7;
        acc2 += A2 * w0 + B2 * w1 + C2 * w2 + D2 * w3 + E2 * w4 + F2 * w5 + G2 * w6 + H2 * w7;
        acc3 += A3 * w0 + B3 * w1 + C3 * w2 + D3 * w3 + E3 * w4 + F3 * w5 + G3 * w6 + H3 * w7;
        acc4 += A4 * w0 + B4 * w1 + C4 * w2 + D4 * w3 + E4 * w4 + F4 * w5 + G4 * w6 + H4 * w7;
        acc5 += A5 * w0 + B5 * w1 + C5 * w2 + D5 * w3 + E5 * w4 + F5 * w5 + G5 * w6 + H5 * w7;
        acc6 += A6 * w0 + B6 * w1 + C6 * w2 + D6 * w3 + E6 * w4 + F6 * w5 + G6 * w6 + H6 * w7;
        acc7 += A7 * w0 + B7 * w1 + C7 * w2 + D7 * w3 + E7 * w4 + F7 * w5 + G7 * w6 + H7 * w7;
    }
#undef UNP
    acc0 *= dn; acc1 *= dn; acc2 *= dn; acc3 *= dn;
    acc4 *= dn; acc5 *= dn; acc6 *= dn; acc7 *= dn;
    uint4 pk;
    pk.x = bf16rne(acc0) | (bf16rne(acc1) << 16);
    pk.y = bf16rne(acc2) | (bf16rne(acc3) << 16);
    pk.z = bf16rne(acc4) | (bf16rne(acc5) << 16);
    pk.w = bf16rne(acc6) | (bf16rne(acc7) << 16);
    *(uint4*)&tile[local][lane16 * 8] = pk;
    __syncthreads();

    int wave = threadIdx.x >> 6;
    int lane = threadIdx.x & 63;
    int m = lane & 15;
    int quad = lane >> 4;
    f32x4 acc[2] = {};
#pragma unroll
    for (int kc = 0; kc < 4; ++kc) {
        bf16x8 a = *(const bf16x8*)&tile[m][kc * 32 + quad * 8];
#pragma unroll
        for (int ctl = 0; ctl < 2; ++ctl) {
            int ct = wave * 2 + ctl;
            bf16x8 bfr = *(const bf16x8*)(Wt + (size_t)(ct * 16 + m) * 128 + kc * 32 + quad * 8);
            acc[ctl] = __builtin_amdgcn_mfma_f32_16x16x32_bf16(a, bfr, acc[ctl], 0, 0, 0);
        }
    }
#pragma unroll
    for (int ctl = 0; ctl < 2; ++ctl) {
        int col = (wave * 2 + ctl) * 16 + m;
        float bv = bias[col];
#pragma unroll
        for (int r = 0; r < 4; ++r) {
            int nr = onode[quad * 4 + r];
            float v = acc[ctl][r] + bv;
            if (relu) v = fmaxf(v, 0.f);
            outB[(size_t)nr * 128 + col] = (unsigned short)bf16rne(v);
        }
    }
}

// ---------------- pooling stage 1: run-length partial sums over sorted batch -------
#define PCHUNK 49
__global__ __launch_bounds__(128) void pool1_k(const unsigned short* __restrict__ hb,
                                               const int* __restrict__ batch,
                                               float* __restrict__ pool) {
    int c = threadIdx.x;
    int n0 = blockIdx.x * PCHUNK;
    if (n0 >= N_NODES) return;
    int n1 = n0 + PCHUNK;
    if (n1 > N_NODES) n1 = N_NODES;
    int g = batch[n0];
    float run = 0.f;
    for (int n = n0; n < n1; ++n) {
        int gn = batch[n];
        if (gn != g) {
            atomicAdd(&pool[g * 128 + c], run);
            run = 0.f;
            g = gn;
        }
        run += __uint_as_float((unsigned)hb[(size_t)n * 128 + c] << 16);
    }
    atomicAdd(&pool[g * 128 + c], run);
}

// ---------------- classifier: emb = pool/cnt; out = (emb@lw1+lb1)@lw2+lb2 ----------
__global__ __launch_bounds__(128) void cls2_k(const float* __restrict__ pool,
                                              const int* __restrict__ gstart,
                                              const float* __restrict__ lw1,
                                              const float* __restrict__ lb1,
                                              const float* __restrict__ lw2,
                                              const float* __restrict__ lb2,
                                              float* __restrict__ out) {
    __shared__ float emb[128];
    __shared__ float mid[128];
    int g = blockIdx.x, c = threadIdx.x;
    float cntf = fmaxf((float)(gstart[g + 1] - gstart[g]), 1.0f);
    emb[c] = pool[(size_t)g * 128 + c] / cntf;
    __syncthreads();
    float a = lb1[c];
    for (int k = 0; k < 128; ++k) a += emb[k] * lw1[k * 128 + c];
    mid[c] = a;
    __syncthreads();
    if (c < OUT_CH) {
        float o = lb2[c];
        for (int k = 0; k < 128; ++k) o += mid[k] * lw2[k * OUT_CH + c];
        out[g * OUT_CH + c] = o;
    }
}

extern "C" void kernel_launch(void* const* d_in, const int* in_sizes, int n_in,
                              void* d_out, int out_size, void* d_ws, size_t ws_size,
                              hipStream_t stream) {
    const float* x = (const float*)d_in[0];
    const int* ei = (const int*)d_in[1];
    const int* src = ei;
    const int* dst = ei + N_EDGES;
    const float* ew = (const float*)d_in[2];
    const int* batch = (const int*)d_in[3];
    const float* W1 = (const float*)d_in[4];
    const float* b1 = (const float*)d_in[5];
    const float* W2 = (const float*)d_in[6];
    const float* b2 = (const float*)d_in[7];
    const float* W3 = (const float*)d_in[8];
    const float* b3 = (const float*)d_in[9];
    const float* lw1 = (const float*)d_in[10];
    const float* lb1 = (const float*)d_in[11];
    const float* lw2 = (const float*)d_in[12];
    const float* lb2 = (const float*)d_in[13];
    float* out = (float*)d_out;

    char* ws = (char*)d_ws;
    size_t off = 0;
    auto alloc = [&](size_t bytes) {
        size_t cur = off;
        off += (bytes + 255) & ~(size_t)255;
        return cur;
    };
    size_t o_bcount = alloc(NBUCK * 4);
    size_t o_pool = alloc(N_GRAPHS * HID * 4);
    size_t o_deghist = alloc(128 * 4);
    size_t zero_end = off;
    size_t o_bincur = alloc(128 * 4);
    size_t o_fill = alloc(N_NODES * 4);
    size_t o_dinv = alloc(N_NODES * 4);
    size_t o_order = alloc(N_NODES * 4);
    size_t o_gstart = alloc((N_GRAPHS + 1) * 4);
    size_t o_wt = alloc(3 * 16384 * 2);
    size_t o_loff = alloc((size_t)NBUCK * BNODES * NR * 4);
    size_t o_ell = alloc((size_t)N_NODES * PAD_T * 8);
    size_t o_cpair = alloc((size_t)NBUCK * BCAP * 8);
    size_t o_featA = alloc((size_t)N_NODES * HID * 2);
    size_t o_featB = alloc((size_t)N_NODES * HID * 2);
    (void)ws_size;

    int* bcount = (int*)(ws + o_bcount);
    float* pool = (float*)(ws + o_pool);
    int* deghist = (int*)(ws + o_deghist);
    int* bincur = (int*)(ws + o_bincur);
    int* fill = (int*)(ws + o_fill);
    float* dinv = (float*)(ws + o_dinv);
    int* order = (int*)(ws + o_order);
    int* gstart = (int*)(ws + o_gstart);
    unsigned short* Wt = (unsigned short*)(ws + o_wt);
    int* loff = (int*)(ws + o_loff);
    int2* ell = (int2*)(ws + o_ell);
    int2* cpair = (int2*)(ws + o_cpair);
    unsigned short* featA = (unsigned short*)(ws + o_featA);
    unsigned short* featB = (unsigned short*)(ws + o_featB);

    hipMemsetAsync(d_ws, 0, zero_end, stream);

    bucket_k<<<P1BLK, 1024, 0, stream>>>(src, dst, ew, bcount, cpair);
    ellcount_k<<<NBUCK, 512, 0, stream>>>(bcount, cpair, loff, fill, dinv, deghist, ell);
    ellfill_k<<<NBUCK, 512, 0, stream>>>(bcount, cpair, loff, dinv, ell);
    dprefix_k<<<1, 128, 0, stream>>>(deghist, bincur);
    prep_k<<<196, 256, 0, stream>>>(batch, gstart, W1, W2, W3, Wt);
    xconv_k<<<(N_NODES * 16 + 255) / 256, 256, 0, stream>>>(x, featA, fill, bincur, order);

    int agg_blocks = (N_NODES + 15) / 16;  // 3125, *16 == N_NODES exactly
    aggemm_k<<<agg_blocks, 256, 0, stream>>>(featA, order, fill, ell, dinv, Wt, b1, featB, 1);
    aggemm_k<<<agg_blocks, 256, 0, stream>>>(featB, order, fill, ell, dinv, Wt + 16384, b2, featA, 1);
    aggemm_k<<<agg_blocks, 256, 0, stream>>>(featA, order, fill, ell, dinv, Wt + 32768, b3, featB, 0);

    pool1_k<<<(N_NODES + PCHUNK - 1) / PCHUNK, 128, 0, stream>>>(featB, batch, pool);
    cls2_k<<<N_GRAPHS, 128, 0, stream>>>(pool, gstart, lw1, lb1, lw2, lb2, out);
}

// Round 4
// 435.207 us; speedup vs baseline: 1.6404x; 1.6404x over previous
//
#include <hip/hip_runtime.h>

#define N_NODES 50000
#define N_EDGES 1600000
#define N_GRAPHS 256
#define HID 128
#define OUT_CH 10
#define NBUCK 512    // dst buckets for two-phase build
#define BNODES ((N_NODES + NBUCK - 1) / NBUCK)  // 98 nodes per bucket
#define BCAP 6144    // slots per bucket region
#define P1BLK 250    // phase-1 blocks (EPB = 6400, divisible by 4)
#define EPB (N_EDGES / P1BLK)
#define DSENTINEL 127  // dloc sentinel for alignment-pad slots (valid dloc < 98)
#define NR 4           // src ranges for L2-windowed gather
#define RSTEP ((N_NODES + NR - 1) / NR)  // 12500 -> 3.2 MB feature window / range
#define PAD_R 40       // slots per (node, range); global max deg <80, per-range max ~30

typedef __bf16 bf16x8 __attribute__((ext_vector_type(8)));
typedef float f32x4 __attribute__((ext_vector_type(4)));

__device__ inline unsigned bf16rne(float f) {
    unsigned u = __float_as_uint(f);
    return (u + 0x7fffu + ((u >> 16) & 1u)) >> 16;
}

// cpair payload: .x = (dloc<<16) | src   (src < 65536, dloc < 98), .y = bitcast w
// ---------------- phase 1: bucket edges, line-aligned per-block reservations -------
__global__ __launch_bounds__(1024) void bucket_k(const int* __restrict__ src,
                                                 const int* __restrict__ dst,
                                                 const float* __restrict__ ew,
                                                 int* __restrict__ bcount,
                                                 int2* __restrict__ cpair) {
    __shared__ int hist[NBUCK];
    __shared__ int base[NBUCK];
    int t = threadIdx.x;
    for (int i = t; i < NBUCK; i += 1024) hist[i] = 0;
    __syncthreads();
    const int ch0 = blockIdx.x * (EPB / 4);
    const int ch1 = ch0 + (EPB / 4);
    const int4* dst4 = (const int4*)dst;
    for (int ci = ch0 + t; ci < ch1; ci += 1024) {
        int4 d4 = dst4[ci];
        atomicAdd(&hist[d4.x / BNODES], 1);
        atomicAdd(&hist[d4.y / BNODES], 1);
        atomicAdd(&hist[d4.z / BNODES], 1);
        atomicAdd(&hist[d4.w / BNODES], 1);
    }
    __syncthreads();
    // reserve line-aligned ranges (8 slots = 64 B): every cpair line owned by ONE block
    for (int i = t; i < NBUCK; i += 1024) {
        int c = hist[i];
        base[i] = (c > 0) ? atomicAdd(&bcount[i], (c + 7) & ~7) : 0;
        hist[i] = 0;  // reuse as within-reservation cursor
    }
    __syncthreads();
    for (int ci = ch0 + t; ci < ch1; ci += 1024) {
        int4 d4 = dst4[ci];
        int e = ci * 4;
#define PROC(dd, ee)                                              \
        {                                                         \
            int b = (dd) / BNODES;                                \
            int off = base[b] + atomicAdd(&hist[b], 1);           \
            if (off < BCAP) {                                     \
                int2 p;                                           \
                p.x = (((dd) - b * BNODES) << 16) | src[ee];      \
                p.y = __float_as_int(ew[ee]);                     \
                cpair[b * BCAP + off] = p;                        \
            }                                                     \
        }
        PROC(d4.x, e)
        PROC(d4.y, e + 1)
        PROC(d4.z, e + 2)
        PROC(d4.w, e + 3)
#undef PROC
    }
    __syncthreads();
    // pad slack slots [c, align8(c)) with sentinel so phase 2 can skip them
    for (int i = t; i < NBUCK; i += 1024) {
        int c = hist[i];
        int ac = (c + 7) & ~7;
        for (int j = c; j < ac; ++j) {
            int off = base[i] + j;
            if (off < BCAP) {
                int2 p;
                p.x = DSENTINEL << 16;
                p.y = 0;
                cpair[i * BCAP + off] = p;
            }
        }
    }
}

// ---------------- phase 2: bucket -> src-range-bucketed ELL + fill4 + dinv ---------
// ELL layout: [n][r][PAD_R]; fill4[n] = packed uchar4 counts ROUNDED UP to mult-4;
// slots [c, round4(c)) are zero entries (src=0, w=0) so the gather loop has no tail.
__global__ __launch_bounds__(512) void ell_scatter_k(const int* __restrict__ bcount,
                                                     const int2* __restrict__ cpair,
                                                     int2* __restrict__ ell,
                                                     unsigned* __restrict__ fill4,
                                                     float* __restrict__ dinv) {
    __shared__ int lfill[BNODES * NR];
    __shared__ float wsum[BNODES];
    int b = blockIdx.x;
    int t = threadIdx.x;
    for (int i = t; i < BNODES * NR; i += 512) lfill[i] = 0;
    for (int i = t; i < BNODES; i += 512) wsum[i] = 0.f;
    __syncthreads();
    int cnt = bcount[b];
    if (cnt > BCAP) cnt = BCAP;
    int n0 = b * BNODES;
    int sbase = b * BCAP;
    for (int i = t; i < cnt; i += 512) {
        int2 p = cpair[sbase + i];
        int dloc = p.x >> 16;
        if (dloc < BNODES) {
            int s = p.x & 0xffff;
            int r = s / RSTEP;
            int pos = atomicAdd(&lfill[dloc * NR + r], 1);
            atomicAdd(&wsum[dloc], __int_as_float(p.y));
            if (pos < PAD_R) {
                int2 q;
                q.x = s;
                q.y = p.y;
                ell[((size_t)(n0 + dloc) * NR + r) * PAD_R + pos] = q;
            }
        }
    }
    __syncthreads();
    for (int i = t; i < BNODES; i += 512) {
        int n = n0 + i;
        if (n < N_NODES) {
            unsigned f = 0;
            int2 z; z.x = 0; z.y = 0;
#pragma unroll
            for (int r = 0; r < NR; ++r) {
                int c = lfill[i * NR + r];
                if (c > PAD_R) c = PAD_R;
                int cp = (c + 3) & ~3;          // mult-4 (<= PAD_R since PAD_R%4==0)
                for (int j = c; j < cp; ++j)     // zero-pad: w=0 contributes nothing
                    ell[((size_t)n * NR + r) * PAD_R + j] = z;
                f |= (unsigned)cp << (8 * r);
            }
            fill4[n] = f;
            dinv[n] = rsqrtf(wsum[i] + 1.0f);
        }
    }
}

// ---------------- fused prep: graph boundaries + W bf16 transpose ------------------
__global__ __launch_bounds__(256) void prep_k(const int* __restrict__ batch,
                                              int* __restrict__ gstart,
                                              const float* __restrict__ W1,
                                              const float* __restrict__ W2,
                                              const float* __restrict__ W3,
                                              unsigned short* __restrict__ Wt) {
    int idx = blockIdx.x * 256 + threadIdx.x;
    if (idx < 3 * 16384) {
        int m = idx >> 14;
        int r = idx & 16383;
        const float* W = (m == 0) ? W1 : (m == 1) ? W2 : W3;
        int c = r >> 7, k = r & 127;
        Wt[idx] = (unsigned short)bf16rne(W[k * 128 + c]);
    }
    if (idx < N_NODES) {
        int b = batch[idx];
        int bprev = (idx == 0) ? -1 : batch[idx - 1];
        for (int g = bprev + 1; g <= b; ++g) gstart[g] = idx;
        if (idx == N_NODES - 1) {
            for (int g = b + 1; g <= N_GRAPHS; ++g) gstart[g] = N_NODES;
        }
    }
}

// ---------------- one-time x fp32 -> bf16 convert (layer-1 gather table) -----------
__global__ __launch_bounds__(256) void xconv_k(const float* __restrict__ x,
                                               unsigned short* __restrict__ xb) {
    int i = blockIdx.x * 256 + threadIdx.x;  // one thread per 8 channels
    if (i >= N_NODES * 16) return;
    const float4* p = (const float4*)x + (size_t)i * 2;
    float4 lo = p[0], hi = p[1];
    uint4 pk;
    pk.x = bf16rne(lo.x) | (bf16rne(lo.y) << 16);
    pk.y = bf16rne(lo.z) | (bf16rne(lo.w) << 16);
    pk.z = bf16rne(hi.x) | (bf16rne(hi.y) << 16);
    pk.w = bf16rne(hi.z) | (bf16rne(hi.w) << 16);
    ((uint4*)xb)[i] = pk;
}

// ---------------- fused layer: out = relu( agg(x) @ W + b ), wave-local ------------
// Each wave owns 4 nodes; aggregated rows go to a PRIVATE 4x140 LDS slab and the
// MFMA tail runs immediately (A rows 0-3 valid, 4-15 duplicates whose outputs are
// discarded; MFMA pipe is idle so 4x waste is free). NO __syncthreads: producer and
// consumer are the same wave -> waves retire independently (no straggler coupling).
__global__ __launch_bounds__(256, 4) void aggemm_k(const unsigned short* __restrict__ tb,
                                                   const unsigned* __restrict__ fill4,
                                                   const int2* __restrict__ ell,
                                                   const float* __restrict__ dinv,
                                                   const unsigned short* __restrict__ Wt,
                                                   const float* __restrict__ bias,
                                                   unsigned short* __restrict__ outB,
                                                   int relu) {
    __shared__ unsigned short tile[4][4][140];  // [wave][node][ch]; 280B row stride
    int lane16 = threadIdx.x & 15;
    int local = threadIdx.x >> 4;
    int wave = threadIdx.x >> 6;
    int n = blockIdx.x * 16 + local;  // 3125*16 == N_NODES exactly, no guard
    float dn = dinv[n];
#define UNP(q, f)                                                 \
    float f##0 = __uint_as_float((q).x << 16);                    \
    float f##1 = __uint_as_float((q).x & 0xffff0000u);            \
    float f##2 = __uint_as_float((q).y << 16);                    \
    float f##3 = __uint_as_float((q).y & 0xffff0000u);            \
    float f##4 = __uint_as_float((q).z << 16);                    \
    float f##5 = __uint_as_float((q).z & 0xffff0000u);            \
    float f##6 = __uint_as_float((q).w << 16);                    \
    float f##7 = __uint_as_float((q).w & 0xffff0000u);
    uint4 qs = ((const uint4*)(tb + (size_t)n * 128))[lane16];
    UNP(qs, S)
    float acc0 = S0 * dn, acc1 = S1 * dn, acc2 = S2 * dn, acc3 = S3 * dn;
    float acc4 = S4 * dn, acc5 = S5 * dn, acc6 = S6 * dn, acc7 = S7 * dn;
    unsigned f4 = fill4[n];
#pragma unroll
    for (int r = 0; r < NR; ++r) {
        int c = (f4 >> (8 * r)) & 255;  // already a multiple of 4 (zero-padded)
        const int2* ep = ell + ((size_t)n * NR + r) * PAD_R;
        for (int i = 0; i < c; i += 4) {
            int2 p0 = ep[i], p1 = ep[i + 1], p2 = ep[i + 2], p3 = ep[i + 3];
            uint4 q0 = ((const uint4*)(tb + (size_t)p0.x * 128))[lane16];
            uint4 q1 = ((const uint4*)(tb + (size_t)p1.x * 128))[lane16];
            uint4 q2 = ((const uint4*)(tb + (size_t)p2.x * 128))[lane16];
            uint4 q3 = ((const uint4*)(tb + (size_t)p3.x * 128))[lane16];
            float w0 = __int_as_float(p0.y) * dinv[p0.x];
            float w1 = __int_as_float(p1.y) * dinv[p1.x];
            float w2 = __int_as_float(p2.y) * dinv[p2.x];
            float w3 = __int_as_float(p3.y) * dinv[p3.x];
            UNP(q0, A)
            UNP(q1, B)
            UNP(q2, C)
            UNP(q3, D)
            acc0 += A0 * w0 + B0 * w1 + C0 * w2 + D0 * w3;
            acc1 += A1 * w0 + B1 * w1 + C1 * w2 + D1 * w3;
            acc2 += A2 * w0 + B2 * w1 + C2 * w2 + D2 * w3;
            acc3 += A3 * w0 + B3 * w1 + C3 * w2 + D3 * w3;
            acc4 += A4 * w0 + B4 * w1 + C4 * w2 + D4 * w3;
            acc5 += A5 * w0 + B5 * w1 + C5 * w2 + D5 * w3;
            acc6 += A6 * w0 + B6 * w1 + C6 * w2 + D6 * w3;
            acc7 += A7 * w0 + B7 * w1 + C7 * w2 + D7 * w3;
        }
    }
#undef UNP
    // finish aggregation (outer dn scale), round to bf16 into this wave's LDS slab
    acc0 *= dn; acc1 *= dn; acc2 *= dn; acc3 *= dn;
    acc4 *= dn; acc5 *= dn; acc6 *= dn; acc7 *= dn;
    uint4 pk;
    pk.x = bf16rne(acc0) | (bf16rne(acc1) << 16);
    pk.y = bf16rne(acc2) | (bf16rne(acc3) << 16);
    pk.z = bf16rne(acc4) | (bf16rne(acc5) << 16);
    pk.w = bf16rne(acc6) | (bf16rne(acc7) << 16);
    *(uint4*)&tile[wave][local & 3][lane16 * 8] = pk;
    // same-wave LDS dependency: compiler inserts lgkmcnt wait, no barrier needed

    // MFMA tail: C[0..3][128] = waveTile(4x128, rows duplicated to 16) @ W
    int quad = (threadIdx.x >> 4) & 3;   // == local & 3
    int mm = lane16;                     // A row / output col within 16-col tile
    f32x4 acc[8] = {};
#pragma unroll
    for (int kc = 0; kc < 4; ++kc) {
        bf16x8 a = *(const bf16x8*)&tile[wave][mm & 3][(kc * 4 + quad) * 8];
#pragma unroll
        for (int ct = 0; ct < 8; ++ct) {
            bf16x8 bfr = *(const bf16x8*)(Wt + (size_t)(ct * 16 + mm) * 128 + kc * 32 + quad * 8);
            acc[ct] = __builtin_amdgcn_mfma_f32_16x16x32_bf16(a, bfr, acc[ct], 0, 0, 0);
        }
    }
    if (quad == 0) {  // C rows 0..3 (the wave's 4 nodes) live in quad-0 lanes
        int nb = blockIdx.x * 16 + wave * 4;
#pragma unroll
        for (int ct = 0; ct < 8; ++ct) {
            float bv = bias[ct * 16 + mm];
#pragma unroll
            for (int r = 0; r < 4; ++r) {
                float v = acc[ct][r] + bv;
                if (relu) v = fmaxf(v, 0.f);
                outB[(size_t)(nb + r) * 128 + ct * 16 + mm] = (unsigned short)bf16rne(v);
            }
        }
    }
}

// ---------------- pooling stage 1: run-length partial sums over sorted batch -------
#define PCHUNK 49
__global__ __launch_bounds__(128) void pool1_k(const unsigned short* __restrict__ hb,
                                               const int* __restrict__ batch,
                                               float* __restrict__ pool) {
    int c = threadIdx.x;
    int n0 = blockIdx.x * PCHUNK;
    if (n0 >= N_NODES) return;
    int n1 = n0 + PCHUNK;
    if (n1 > N_NODES) n1 = N_NODES;
    int g = batch[n0];
    float run = 0.f;
    for (int n = n0; n < n1; ++n) {
        int gn = batch[n];
        if (gn != g) {
            atomicAdd(&pool[g * 128 + c], run);
            run = 0.f;
            g = gn;
        }
        run += __uint_as_float((unsigned)hb[(size_t)n * 128 + c] << 16);
    }
    atomicAdd(&pool[g * 128 + c], run);
}

// ---------------- classifier: emb = pool/cnt; out = (emb@lw1+lb1)@lw2+lb2 ----------
__global__ __launch_bounds__(128) void cls2_k(const float* __restrict__ pool,
                                              const int* __restrict__ gstart,
                                              const float* __restrict__ lw1,
                                              const float* __restrict__ lb1,
                                              const float* __restrict__ lw2,
                                              const float* __restrict__ lb2,
                                              float* __restrict__ out) {
    __shared__ float emb[128];
    __shared__ float mid[128];
    int g = blockIdx.x, c = threadIdx.x;
    float cntf = fmaxf((float)(gstart[g + 1] - gstart[g]), 1.0f);
    emb[c] = pool[(size_t)g * 128 + c] / cntf;
    __syncthreads();
    float a = lb1[c];
    for (int k = 0; k < 128; ++k) a += emb[k] * lw1[k * 128 + c];
    mid[c] = a;
    __syncthreads();
    if (c < OUT_CH) {
        float o = lb2[c];
        for (int k = 0; k < 128; ++k) o += mid[k] * lw2[k * OUT_CH + c];
        out[g * OUT_CH + c] = o;
    }
}

extern "C" void kernel_launch(void* const* d_in, const int* in_sizes, int n_in,
                              void* d_out, int out_size, void* d_ws, size_t ws_size,
                              hipStream_t stream) {
    const float* x = (const float*)d_in[0];
    const int* ei = (const int*)d_in[1];
    const int* src = ei;
    const int* dst = ei + N_EDGES;
    const float* ew = (const float*)d_in[2];
    const int* batch = (const int*)d_in[3];
    const float* W1 = (const float*)d_in[4];
    const float* b1 = (const float*)d_in[5];
    const float* W2 = (const float*)d_in[6];
    const float* b2 = (const float*)d_in[7];
    const float* W3 = (const float*)d_in[8];
    const float* b3 = (const float*)d_in[9];
    const float* lw1 = (const float*)d_in[10];
    const float* lb1 = (const float*)d_in[11];
    const float* lw2 = (const float*)d_in[12];
    const float* lb2 = (const float*)d_in[13];
    float* out = (float*)d_out;

    char* ws = (char*)d_ws;
    size_t off = 0;
    auto alloc = [&](size_t bytes) {
        size_t cur = off;
        off += (bytes + 255) & ~(size_t)255;
        return cur;
    };
    // zero-init region (one memset): bucket counters + pool sums
    size_t o_bcount = alloc(NBUCK * 4);
    size_t o_pool = alloc(N_GRAPHS * HID * 4);
    size_t zero_end = off;
    // rest
    size_t o_fill4 = alloc(N_NODES * 4);
    size_t o_dinv = alloc(N_NODES * 4);
    size_t o_gstart = alloc((N_GRAPHS + 1) * 4);
    size_t o_wt = alloc(3 * 16384 * 2);
    size_t o_ell = alloc((size_t)N_NODES * NR * PAD_R * 8);
    size_t o_cpair = alloc((size_t)NBUCK * BCAP * 8);
    size_t o_featA = alloc((size_t)N_NODES * HID * 2);  // feature ping (bf16)
    size_t o_featB = alloc((size_t)N_NODES * HID * 2);  // feature pong (bf16)
    (void)ws_size;

    int* bcount = (int*)(ws + o_bcount);
    float* pool = (float*)(ws + o_pool);
    unsigned* fill4 = (unsigned*)(ws + o_fill4);
    float* dinv = (float*)(ws + o_dinv);
    int* gstart = (int*)(ws + o_gstart);
    unsigned short* Wt = (unsigned short*)(ws + o_wt);
    int2* ell = (int2*)(ws + o_ell);
    int2* cpair = (int2*)(ws + o_cpair);
    unsigned short* featA = (unsigned short*)(ws + o_featA);
    unsigned short* featB = (unsigned short*)(ws + o_featB);

    hipMemsetAsync(d_ws, 0, zero_end, stream);

    // two-phase ELL build (line-aligned reservations, src-range-bucketed rows)
    bucket_k<<<P1BLK, 1024, 0, stream>>>(src, dst, ew, bcount, cpair);
    ell_scatter_k<<<NBUCK, 512, 0, stream>>>(bcount, cpair, ell, fill4, dinv);
    prep_k<<<196, 256, 0, stream>>>(batch, gstart, W1, W2, W3, Wt);
    xconv_k<<<(N_NODES * 16 + 255) / 256, 256, 0, stream>>>(x, featA);

    int agg_blocks = (N_NODES + 15) / 16;  // 3125, *16 == N_NODES exactly
    // fused layers: out = relu?( agg(feat) @ W + b ), wave-local MFMA tail
    aggemm_k<<<agg_blocks, 256, 0, stream>>>(featA, fill4, ell, dinv, Wt, b1, featB, 1);
    aggemm_k<<<agg_blocks, 256, 0, stream>>>(featB, fill4, ell, dinv, Wt + 16384, b2, featA, 1);
    aggemm_k<<<agg_blocks, 256, 0, stream>>>(featA, fill4, ell, dinv, Wt + 32768, b3, featB, 0);

    // two-stage mean-pool (bf16 in) + classify
    pool1_k<<<(N_NODES + PCHUNK - 1) / PCHUNK, 128, 0, stream>>>(featB, batch, pool);
    cls2_k<<<N_GRAPHS, 128, 0, stream>>>(pool, gstart, lw1, lb1, lw2, lb2, out);
}

// Round 5
// 431.262 us; speedup vs baseline: 1.6554x; 1.0091x over previous
//
#include <hip/hip_runtime.h>

#define N_NODES 50000
#define N_EDGES 1600000
#define N_GRAPHS 256
#define HID 128
#define OUT_CH 10
#define NBUCK 512    // dst buckets for two-phase build
#define BNODES ((N_NODES + NBUCK - 1) / NBUCK)  // 98 nodes per bucket
#define BCAP 6144    // slots per bucket region
#define P1BLK 250    // phase-1 blocks (EPB = 6400, divisible by 4)
#define EPB (N_EDGES / P1BLK)
#define DSENTINEL 127  // dloc sentinel for alignment-pad slots (valid dloc < 98)
#define NR 4           // src ranges for L2-windowed gather
#define RSTEP ((N_NODES + NR - 1) / NR)  // 12500 -> 3.2 MB feature window / range
#define PAD_R 40       // slots per (node, range); global max deg <80, per-range max ~30

typedef __bf16 bf16x8 __attribute__((ext_vector_type(8)));
typedef float f32x4 __attribute__((ext_vector_type(4)));

__device__ inline unsigned bf16rne(float f) {
    unsigned u = __float_as_uint(f);
    return (u + 0x7fffu + ((u >> 16) & 1u)) >> 16;
}

// cpair payload: .x = (dloc<<16) | src   (src < 65536, dloc < 98), .y = bitcast w
// ---------------- phase 1: bucket edges + global weighted-degree atomics -----------
__global__ __launch_bounds__(1024) void bucket_k(const int* __restrict__ src,
                                                 const int* __restrict__ dst,
                                                 const float* __restrict__ ew,
                                                 int* __restrict__ bcount,
                                                 int2* __restrict__ cpair,
                                                 float* __restrict__ wsumg) {
    __shared__ int hist[NBUCK];
    __shared__ int base[NBUCK];
    int t = threadIdx.x;
    for (int i = t; i < NBUCK; i += 1024) hist[i] = 0;
    __syncthreads();
    const int ch0 = blockIdx.x * (EPB / 4);
    const int ch1 = ch0 + (EPB / 4);
    const int4* dst4 = (const int4*)dst;
    for (int ci = ch0 + t; ci < ch1; ci += 1024) {
        int4 d4 = dst4[ci];
        atomicAdd(&hist[d4.x / BNODES], 1);
        atomicAdd(&hist[d4.y / BNODES], 1);
        atomicAdd(&hist[d4.z / BNODES], 1);
        atomicAdd(&hist[d4.w / BNODES], 1);
    }
    __syncthreads();
    // reserve line-aligned ranges (8 slots = 64 B): every cpair line owned by ONE block
    for (int i = t; i < NBUCK; i += 1024) {
        int c = hist[i];
        base[i] = (c > 0) ? atomicAdd(&bcount[i], (c + 7) & ~7) : 0;
        hist[i] = 0;  // reuse as within-reservation cursor
    }
    __syncthreads();
    for (int ci = ch0 + t; ci < ch1; ci += 1024) {
        int4 d4 = dst4[ci];
        int e = ci * 4;
#define PROC(dd, ee)                                              \
        {                                                         \
            float w = ew[ee];                                     \
            atomicAdd(&wsumg[dd], w);                             \
            int b = (dd) / BNODES;                                \
            int off = base[b] + atomicAdd(&hist[b], 1);           \
            if (off < BCAP) {                                     \
                int2 p;                                           \
                p.x = (((dd) - b * BNODES) << 16) | src[ee];      \
                p.y = __float_as_int(w);                          \
                cpair[b * BCAP + off] = p;                        \
            }                                                     \
        }
        PROC(d4.x, e)
        PROC(d4.y, e + 1)
        PROC(d4.z, e + 2)
        PROC(d4.w, e + 3)
#undef PROC
    }
    __syncthreads();
    // pad slack slots [c, align8(c)) with sentinel so phase 2 can skip them
    for (int i = t; i < NBUCK; i += 1024) {
        int c = hist[i];
        int ac = (c + 7) & ~7;
        for (int j = c; j < ac; ++j) {
            int off = base[i] + j;
            if (off < BCAP) {
                int2 p;
                p.x = DSENTINEL << 16;
                p.y = 0;
                cpair[i * BCAP + off] = p;
            }
        }
    }
}

// ---------------- fused prep: graph bounds + W bf16 transpose + dinv ---------------
__global__ __launch_bounds__(256) void prep_k(const int* __restrict__ batch,
                                              int* __restrict__ gstart,
                                              const float* __restrict__ W1,
                                              const float* __restrict__ W2,
                                              const float* __restrict__ W3,
                                              unsigned short* __restrict__ Wt,
                                              const float* __restrict__ wsumg,
                                              float* __restrict__ dinv) {
    int idx = blockIdx.x * 256 + threadIdx.x;
    if (idx < 3 * 16384) {
        int m = idx >> 14;
        int r = idx & 16383;
        const float* W = (m == 0) ? W1 : (m == 1) ? W2 : W3;
        int c = r >> 7, k = r & 127;
        Wt[idx] = (unsigned short)bf16rne(W[k * 128 + c]);
    }
    if (idx < N_NODES) {
        dinv[idx] = rsqrtf(wsumg[idx] + 1.0f);  // self-loop weight 1; deg >= 1
        int b = batch[idx];
        int bprev = (idx == 0) ? -1 : batch[idx - 1];
        for (int g = bprev + 1; g <= b; ++g) gstart[g] = idx;
        if (idx == N_NODES - 1) {
            for (int g = b + 1; g <= N_GRAPHS; ++g) gstart[g] = N_NODES;
        }
    }
}

// ---------------- phase 2: bucket -> ELL with PREMULTIPLIED weights + mult-4 pad ---
// ELL layout: [n][r][PAD_R]; payload .y = w * dinv[src] (the same single f32 mul the
// gather used to do per-edge, done once here). fill4 counts rounded up to mult-4;
// slots [c, round4(c)) zeroed so the gather loop is pure 4-wide, no tail.
__global__ __launch_bounds__(512) void ell_scatter_k(const int* __restrict__ bcount,
                                                     const int2* __restrict__ cpair,
                                                     const float* __restrict__ dinv,
                                                     int2* __restrict__ ell,
                                                     unsigned* __restrict__ fill4) {
    __shared__ int lfill[BNODES * NR];
    int b = blockIdx.x;
    int t = threadIdx.x;
    for (int i = t; i < BNODES * NR; i += 512) lfill[i] = 0;
    __syncthreads();
    int cnt = bcount[b];
    if (cnt > BCAP) cnt = BCAP;
    int n0 = b * BNODES;
    int sbase = b * BCAP;
    for (int i = t; i < cnt; i += 512) {
        int2 p = cpair[sbase + i];
        int dloc = p.x >> 16;
        if (dloc < BNODES) {
            int s = p.x & 0xffff;
            int r = s / RSTEP;
            int pos = atomicAdd(&lfill[dloc * NR + r], 1);
            if (pos < PAD_R) {
                int2 q;
                q.x = s;
                q.y = __float_as_int(__int_as_float(p.y) * dinv[s]);  // premultiplied
                ell[((size_t)(n0 + dloc) * NR + r) * PAD_R + pos] = q;
            }
        }
    }
    __syncthreads();
    for (int i = t; i < BNODES; i += 512) {
        int n = n0 + i;
        if (n < N_NODES) {
            unsigned f = 0;
            int2 z; z.x = 0; z.y = 0;
#pragma unroll
            for (int r = 0; r < NR; ++r) {
                int c = lfill[i * NR + r];
                if (c > PAD_R) c = PAD_R;
                int cp = (c + 3) & ~3;           // mult-4 (<= PAD_R, PAD_R%4==0)
                for (int j = c; j < cp; ++j)      // zero-pad: w=0 contributes nothing
                    ell[((size_t)n * NR + r) * PAD_R + j] = z;
                f |= (unsigned)cp << (8 * r);
            }
            fill4[n] = f;
        }
    }
}

// ---------------- one-time x fp32 -> bf16 convert (layer-1 gather table) -----------
__global__ __launch_bounds__(256) void xconv_k(const float* __restrict__ x,
                                               unsigned short* __restrict__ xb) {
    int i = blockIdx.x * 256 + threadIdx.x;  // one thread per 8 channels
    if (i >= N_NODES * 16) return;
    const float4* p = (const float4*)x + (size_t)i * 2;
    float4 lo = p[0], hi = p[1];
    uint4 pk;
    pk.x = bf16rne(lo.x) | (bf16rne(lo.y) << 16);
    pk.y = bf16rne(lo.z) | (bf16rne(lo.w) << 16);
    pk.z = bf16rne(hi.x) | (bf16rne(hi.y) << 16);
    pk.w = bf16rne(hi.z) | (bf16rne(hi.w) << 16);
    ((uint4*)xb)[i] = pk;
}

// ---------------- fused layer: out = relu( agg(x) @ W + b ) ------------------------
// Round-1 skeleton (best measured): 16 nodes/block, 16 lanes/node, barrier, 2-MFMA
// phase-B per wave. Gather: premultiplied weights (1 VMEM op/edge), pure 4-wide
// mult-4-padded loop, unroll 2 -> 8 feature loads in flight.
__global__ __launch_bounds__(256, 6) void aggemm_k(const unsigned short* __restrict__ tb,
                                                   const unsigned* __restrict__ fill4,
                                                   const int2* __restrict__ ell,
                                                   const float* __restrict__ dinv,
                                                   const unsigned short* __restrict__ Wt,
                                                   const float* __restrict__ bias,
                                                   unsigned short* __restrict__ outB,
                                                   int relu) {
    __shared__ unsigned short tile[16][136];  // 272 B row stride: 4-bank row shift
    int lane16 = threadIdx.x & 15;
    int local = threadIdx.x >> 4;
    int n = blockIdx.x * 16 + local;  // 3125*16 == N_NODES exactly, no guard
    float dn = dinv[n];
#define UNP(q, f)                                                 \
    float f##0 = __uint_as_float((q).x << 16);                    \
    float f##1 = __uint_as_float((q).x & 0xffff0000u);            \
    float f##2 = __uint_as_float((q).y << 16);                    \
    float f##3 = __uint_as_float((q).y & 0xffff0000u);            \
    float f##4 = __uint_as_float((q).z << 16);                    \
    float f##5 = __uint_as_float((q).z & 0xffff0000u);            \
    float f##6 = __uint_as_float((q).w << 16);                    \
    float f##7 = __uint_as_float((q).w & 0xffff0000u);
    uint4 qs = ((const uint4*)(tb + (size_t)n * 128))[lane16];
    UNP(qs, S)
    float acc0 = S0 * dn, acc1 = S1 * dn, acc2 = S2 * dn, acc3 = S3 * dn;
    float acc4 = S4 * dn, acc5 = S5 * dn, acc6 = S6 * dn, acc7 = S7 * dn;
    unsigned f4 = fill4[n];
#pragma unroll
    for (int r = 0; r < NR; ++r) {
        int c = (f4 >> (8 * r)) & 255;  // multiple of 4 (zero-padded at build)
        const int2* ep = ell + ((size_t)n * NR + r) * PAD_R;
#pragma unroll 2
        for (int i = 0; i < c; i += 4) {
            int2 p0 = ep[i], p1 = ep[i + 1], p2 = ep[i + 2], p3 = ep[i + 3];
            uint4 q0 = ((const uint4*)(tb + (size_t)p0.x * 128))[lane16];
            uint4 q1 = ((const uint4*)(tb + (size_t)p1.x * 128))[lane16];
            uint4 q2 = ((const uint4*)(tb + (size_t)p2.x * 128))[lane16];
            uint4 q3 = ((const uint4*)(tb + (size_t)p3.x * 128))[lane16];
            float w0 = __int_as_float(p0.y);
            float w1 = __int_as_float(p1.y);
            float w2 = __int_as_float(p2.y);
            float w3 = __int_as_float(p3.y);
            UNP(q0, A)
            UNP(q1, B)
            UNP(q2, C)
            UNP(q3, D)
            acc0 += A0 * w0 + B0 * w1 + C0 * w2 + D0 * w3;
            acc1 += A1 * w0 + B1 * w1 + C1 * w2 + D1 * w3;
            acc2 += A2 * w0 + B2 * w1 + C2 * w2 + D2 * w3;
            acc3 += A3 * w0 + B3 * w1 + C3 * w2 + D3 * w3;
            acc4 += A4 * w0 + B4 * w1 + C4 * w2 + D4 * w3;
            acc5 += A5 * w0 + B5 * w1 + C5 * w2 + D5 * w3;
            acc6 += A6 * w0 + B6 * w1 + C6 * w2 + D6 * w3;
            acc7 += A7 * w0 + B7 * w1 + C7 * w2 + D7 * w3;
        }
    }
#undef UNP
    // finish aggregation (outer dn scale), round to bf16 into the LDS tile
    acc0 *= dn; acc1 *= dn; acc2 *= dn; acc3 *= dn;
    acc4 *= dn; acc5 *= dn; acc6 *= dn; acc7 *= dn;
    uint4 pk;
    pk.x = bf16rne(acc0) | (bf16rne(acc1) << 16);
    pk.y = bf16rne(acc2) | (bf16rne(acc3) << 16);
    pk.z = bf16rne(acc4) | (bf16rne(acc5) << 16);
    pk.w = bf16rne(acc6) | (bf16rne(acc7) << 16);
    *(uint4*)&tile[local][lane16 * 8] = pk;
    __syncthreads();

    // Phase B: C[16][128] = tile @ W; wave w owns output cols [w*32, w*32+32)
    int wave = threadIdx.x >> 6;
    int lane = threadIdx.x & 63;
    int m = lane & 15;
    int quad = lane >> 4;
    f32x4 acc[2] = {};
#pragma unroll
    for (int kc = 0; kc < 4; ++kc) {
        bf16x8 a = *(const bf16x8*)&tile[m][kc * 32 + quad * 8];
#pragma unroll
        for (int ctl = 0; ctl < 2; ++ctl) {
            int ct = wave * 2 + ctl;
            bf16x8 bfr = *(const bf16x8*)(Wt + (size_t)(ct * 16 + m) * 128 + kc * 32 + quad * 8);
            acc[ctl] = __builtin_amdgcn_mfma_f32_16x16x32_bf16(a, bfr, acc[ctl], 0, 0, 0);
        }
    }
#pragma unroll
    for (int ctl = 0; ctl < 2; ++ctl) {
        int col = (wave * 2 + ctl) * 16 + m;
        float bv = bias[col];
#pragma unroll
        for (int r = 0; r < 4; ++r) {
            int nr = blockIdx.x * 16 + quad * 4 + r;
            float v = acc[ctl][r] + bv;
            if (relu) v = fmaxf(v, 0.f);
            outB[(size_t)nr * 128 + col] = (unsigned short)bf16rne(v);
        }
    }
}

// ---------------- pooling stage 1: run-length partial sums over sorted batch -------
#define PCHUNK 49
__global__ __launch_bounds__(128) void pool1_k(const unsigned short* __restrict__ hb,
                                               const int* __restrict__ batch,
                                               float* __restrict__ pool) {
    int c = threadIdx.x;
    int n0 = blockIdx.x * PCHUNK;
    if (n0 >= N_NODES) return;
    int n1 = n0 + PCHUNK;
    if (n1 > N_NODES) n1 = N_NODES;
    int g = batch[n0];
    float run = 0.f;
    for (int n = n0; n < n1; ++n) {
        int gn = batch[n];
        if (gn != g) {
            atomicAdd(&pool[g * 128 + c], run);
            run = 0.f;
            g = gn;
        }
        run += __uint_as_float((unsigned)hb[(size_t)n * 128 + c] << 16);
    }
    atomicAdd(&pool[g * 128 + c], run);
}

// ---------------- classifier: emb = pool/cnt; out = (emb@lw1+lb1)@lw2+lb2 ----------
__global__ __launch_bounds__(128) void cls2_k(const float* __restrict__ pool,
                                              const int* __restrict__ gstart,
                                              const float* __restrict__ lw1,
                                              const float* __restrict__ lb1,
                                              const float* __restrict__ lw2,
                                              const float* __restrict__ lb2,
                                              float* __restrict__ out) {
    __shared__ float emb[128];
    __shared__ float mid[128];
    int g = blockIdx.x, c = threadIdx.x;
    float cntf = fmaxf((float)(gstart[g + 1] - gstart[g]), 1.0f);
    emb[c] = pool[(size_t)g * 128 + c] / cntf;
    __syncthreads();
    float a = lb1[c];
    for (int k = 0; k < 128; ++k) a += emb[k] * lw1[k * 128 + c];
    mid[c] = a;
    __syncthreads();
    if (c < OUT_CH) {
        float o = lb2[c];
        for (int k = 0; k < 128; ++k) o += mid[k] * lw2[k * OUT_CH + c];
        out[g * OUT_CH + c] = o;
    }
}

extern "C" void kernel_launch(void* const* d_in, const int* in_sizes, int n_in,
                              void* d_out, int out_size, void* d_ws, size_t ws_size,
                              hipStream_t stream) {
    const float* x = (const float*)d_in[0];
    const int* ei = (const int*)d_in[1];
    const int* src = ei;
    const int* dst = ei + N_EDGES;
    const float* ew = (const float*)d_in[2];
    const int* batch = (const int*)d_in[3];
    const float* W1 = (const float*)d_in[4];
    const float* b1 = (const float*)d_in[5];
    const float* W2 = (const float*)d_in[6];
    const float* b2 = (const float*)d_in[7];
    const float* W3 = (const float*)d_in[8];
    const float* b3 = (const float*)d_in[9];
    const float* lw1 = (const float*)d_in[10];
    const float* lb1 = (const float*)d_in[11];
    const float* lw2 = (const float*)d_in[12];
    const float* lb2 = (const float*)d_in[13];
    float* out = (float*)d_out;

    char* ws = (char*)d_ws;
    size_t off = 0;
    auto alloc = [&](size_t bytes) {
        size_t cur = off;
        off += (bytes + 255) & ~(size_t)255;
        return cur;
    };
    // zero-init region (one memset): bucket counters + pool sums + weighted degree
    size_t o_bcount = alloc(NBUCK * 4);
    size_t o_pool = alloc(N_GRAPHS * HID * 4);
    size_t o_wsumg = alloc(N_NODES * 4);
    size_t zero_end = off;
    // rest
    size_t o_fill4 = alloc(N_NODES * 4);
    size_t o_dinv = alloc(N_NODES * 4);
    size_t o_gstart = alloc((N_GRAPHS + 1) * 4);
    size_t o_wt = alloc(3 * 16384 * 2);
    size_t o_ell = alloc((size_t)N_NODES * NR * PAD_R * 8);
    size_t o_cpair = alloc((size_t)NBUCK * BCAP * 8);
    size_t o_featA = alloc((size_t)N_NODES * HID * 2);  // feature ping (bf16)
    size_t o_featB = alloc((size_t)N_NODES * HID * 2);  // feature pong (bf16)
    (void)ws_size;

    int* bcount = (int*)(ws + o_bcount);
    float* pool = (float*)(ws + o_pool);
    float* wsumg = (float*)(ws + o_wsumg);
    unsigned* fill4 = (unsigned*)(ws + o_fill4);
    float* dinv = (float*)(ws + o_dinv);
    int* gstart = (int*)(ws + o_gstart);
    unsigned short* Wt = (unsigned short*)(ws + o_wt);
    int2* ell = (int2*)(ws + o_ell);
    int2* cpair = (int2*)(ws + o_cpair);
    unsigned short* featA = (unsigned short*)(ws + o_featA);
    unsigned short* featB = (unsigned short*)(ws + o_featB);

    hipMemsetAsync(d_ws, 0, zero_end, stream);

    // build: bucket (+wsum atomics) -> prep (dinv ready) -> ELL (premultiplied)
    bucket_k<<<P1BLK, 1024, 0, stream>>>(src, dst, ew, bcount, cpair, wsumg);
    prep_k<<<196, 256, 0, stream>>>(batch, gstart, W1, W2, W3, Wt, wsumg, dinv);
    ell_scatter_k<<<NBUCK, 512, 0, stream>>>(bcount, cpair, dinv, ell, fill4);
    xconv_k<<<(N_NODES * 16 + 255) / 256, 256, 0, stream>>>(x, featA);

    int agg_blocks = (N_NODES + 15) / 16;  // 3125, *16 == N_NODES exactly
    // fused layers: out = relu?( agg(feat) @ W + b )
    aggemm_k<<<agg_blocks, 256, 0, stream>>>(featA, fill4, ell, dinv, Wt, b1, featB, 1);
    aggemm_k<<<agg_blocks, 256, 0, stream>>>(featB, fill4, ell, dinv, Wt + 16384, b2, featA, 1);
    aggemm_k<<<agg_blocks, 256, 0, stream>>>(featA, fill4, ell, dinv, Wt + 32768, b3, featB, 0);

    // two-stage mean-pool (bf16 in) + classify
    pool1_k<<<(N_NODES + PCHUNK - 1) / PCHUNK, 128, 0, stream>>>(featB, batch, pool);
    cls2_k<<<N_GRAPHS, 128, 0, stream>>>(pool, gstart, lw1, lb1, lw2, lb2, out);
}

// Round 6
// 412.540 us; speedup vs baseline: 1.7305x; 1.0454x over previous
//
#include <hip/hip_runtime.h>

#define N_NODES 50000
#define N_EDGES 1600000
#define N_GRAPHS 256
#define HID 128
#define OUT_CH 10
#define NBUCK 512    // dst buckets for two-phase build
#define BNODES ((N_NODES + NBUCK - 1) / NBUCK)  // 98 nodes per bucket
#define BCAP 6144    // slots per bucket region
#define P1BLK 250    // phase-1 blocks (EPB = 6400, divisible by 4)
#define EPB (N_EDGES / P1BLK)
#define DSENTINEL 127  // dloc sentinel for alignment-pad slots (valid dloc < 98)
#define NR 4           // src ranges for L2-windowed gather
#define RSTEP ((N_NODES + NR - 1) / NR)  // 12500 -> 3.2 MB feature window / range
#define PAD_R 40       // slots per (node, range); global max deg <80, per-range max ~30

typedef __bf16 bf16x8 __attribute__((ext_vector_type(8)));
typedef float f32x4 __attribute__((ext_vector_type(4)));

__device__ inline unsigned bf16rne(float f) {
    unsigned u = __float_as_uint(f);
    return (u + 0x7fffu + ((u >> 16) & 1u)) >> 16;
}

// cpair payload: .x = (dloc<<16) | src   (src < 65536, dloc < 98), .y = bitcast w
// ---------------- phase 1: bucket edges, line-aligned per-block reservations -------
__global__ __launch_bounds__(1024) void bucket_k(const int* __restrict__ src,
                                                 const int* __restrict__ dst,
                                                 const float* __restrict__ ew,
                                                 int* __restrict__ bcount,
                                                 int2* __restrict__ cpair) {
    __shared__ int hist[NBUCK];
    __shared__ int base[NBUCK];
    int t = threadIdx.x;
    for (int i = t; i < NBUCK; i += 1024) hist[i] = 0;
    __syncthreads();
    const int ch0 = blockIdx.x * (EPB / 4);
    const int ch1 = ch0 + (EPB / 4);
    const int4* dst4 = (const int4*)dst;
    for (int ci = ch0 + t; ci < ch1; ci += 1024) {
        int4 d4 = dst4[ci];
        atomicAdd(&hist[d4.x / BNODES], 1);
        atomicAdd(&hist[d4.y / BNODES], 1);
        atomicAdd(&hist[d4.z / BNODES], 1);
        atomicAdd(&hist[d4.w / BNODES], 1);
    }
    __syncthreads();
    // reserve line-aligned ranges (8 slots = 64 B): every cpair line owned by ONE block
    for (int i = t; i < NBUCK; i += 1024) {
        int c = hist[i];
        base[i] = (c > 0) ? atomicAdd(&bcount[i], (c + 7) & ~7) : 0;
        hist[i] = 0;  // reuse as within-reservation cursor
    }
    __syncthreads();
    for (int ci = ch0 + t; ci < ch1; ci += 1024) {
        int4 d4 = dst4[ci];
        int e = ci * 4;
#define PROC(dd, ee)                                              \
        {                                                         \
            int b = (dd) / BNODES;                                \
            int off = base[b] + atomicAdd(&hist[b], 1);           \
            if (off < BCAP) {                                     \
                int2 p;                                           \
                p.x = (((dd) - b * BNODES) << 16) | src[ee];      \
                p.y = __float_as_int(ew[ee]);                     \
                cpair[b * BCAP + off] = p;                        \
            }                                                     \
        }
        PROC(d4.x, e)
        PROC(d4.y, e + 1)
        PROC(d4.z, e + 2)
        PROC(d4.w, e + 3)
#undef PROC
    }
    __syncthreads();
    // pad slack slots [c, align8(c)) with sentinel so phase 2 can skip them
    for (int i = t; i < NBUCK; i += 1024) {
        int c = hist[i];
        int ac = (c + 7) & ~7;
        for (int j = c; j < ac; ++j) {
            int off = base[i] + j;
            if (off < BCAP) {
                int2 p;
                p.x = DSENTINEL << 16;
                p.y = 0;
                cpair[i * BCAP + off] = p;
            }
        }
    }
}

// ---------------- phase 2: bucket -> src-range-bucketed ELL + fill4 + dinv ---------
// ELL layout: [n][r][PAD_R]; fill4[n] = packed uchar4 counts ROUNDED UP to mult-4;
// slots [c, round4(c)) are zero entries (src=0, w=0) so the gather loop has no tail.
__global__ __launch_bounds__(512) void ell_scatter_k(const int* __restrict__ bcount,
                                                     const int2* __restrict__ cpair,
                                                     int2* __restrict__ ell,
                                                     unsigned* __restrict__ fill4,
                                                     float* __restrict__ dinv) {
    __shared__ int lfill[BNODES * NR];
    __shared__ float wsum[BNODES];
    int b = blockIdx.x;
    int t = threadIdx.x;
    for (int i = t; i < BNODES * NR; i += 512) lfill[i] = 0;
    for (int i = t; i < BNODES; i += 512) wsum[i] = 0.f;
    __syncthreads();
    int cnt = bcount[b];
    if (cnt > BCAP) cnt = BCAP;
    int n0 = b * BNODES;
    int sbase = b * BCAP;
    for (int i = t; i < cnt; i += 512) {
        int2 p = cpair[sbase + i];
        int dloc = p.x >> 16;
        if (dloc < BNODES) {
            int s = p.x & 0xffff;
            int r = s / RSTEP;
            int pos = atomicAdd(&lfill[dloc * NR + r], 1);
            atomicAdd(&wsum[dloc], __int_as_float(p.y));
            if (pos < PAD_R) {
                int2 q;
                q.x = s;
                q.y = p.y;
                ell[((size_t)(n0 + dloc) * NR + r) * PAD_R + pos] = q;
            }
        }
    }
    __syncthreads();
    for (int i = t; i < BNODES; i += 512) {
        int n = n0 + i;
        if (n < N_NODES) {
            unsigned f = 0;
            int2 z; z.x = 0; z.y = 0;
#pragma unroll
            for (int r = 0; r < NR; ++r) {
                int c = lfill[i * NR + r];
                if (c > PAD_R) c = PAD_R;
                int cp = (c + 3) & ~3;           // mult-4 (<= PAD_R since PAD_R%4==0)
                for (int j = c; j < cp; ++j)      // zero-pad: w=0 contributes nothing
                    ell[((size_t)n * NR + r) * PAD_R + j] = z;
                f |= (unsigned)cp << (8 * r);
            }
            fill4[n] = f;
            dinv[n] = rsqrtf(wsum[i] + 1.0f);
        }
    }
}

// ---------------- fused prep: graph boundaries + W bf16 transpose ------------------
__global__ __launch_bounds__(256) void prep_k(const int* __restrict__ batch,
                                              int* __restrict__ gstart,
                                              const float* __restrict__ W1,
                                              const float* __restrict__ W2,
                                              const float* __restrict__ W3,
                                              unsigned short* __restrict__ Wt) {
    int idx = blockIdx.x * 256 + threadIdx.x;
    if (idx < 3 * 16384) {
        int m = idx >> 14;
        int r = idx & 16383;
        const float* W = (m == 0) ? W1 : (m == 1) ? W2 : W3;
        int c = r >> 7, k = r & 127;
        Wt[idx] = (unsigned short)bf16rne(W[k * 128 + c]);
    }
    if (idx < N_NODES) {
        int b = batch[idx];
        int bprev = (idx == 0) ? -1 : batch[idx - 1];
        for (int g = bprev + 1; g <= b; ++g) gstart[g] = idx;
        if (idx == N_NODES - 1) {
            for (int g = b + 1; g <= N_GRAPHS; ++g) gstart[g] = N_NODES;
        }
    }
}

// ---------------- one-time x fp32 -> bf16 convert (layer-1 gather table) -----------
__global__ __launch_bounds__(256) void xconv_k(const float* __restrict__ x,
                                               unsigned short* __restrict__ xb) {
    int i = blockIdx.x * 256 + threadIdx.x;  // one thread per 8 channels
    if (i >= N_NODES * 16) return;
    const float4* p = (const float4*)x + (size_t)i * 2;
    float4 lo = p[0], hi = p[1];
    uint4 pk;
    pk.x = bf16rne(lo.x) | (bf16rne(lo.y) << 16);
    pk.y = bf16rne(lo.z) | (bf16rne(lo.w) << 16);
    pk.z = bf16rne(hi.x) | (bf16rne(hi.y) << 16);
    pk.w = bf16rne(hi.z) | (bf16rne(hi.w) << 16);
    ((uint4*)xb)[i] = pk;
}

// ---------------- fused layer: out = relu( agg(x) @ W + b ) ------------------------
// Round-1 skeleton (measured best): 16 nodes/block, 16 lanes/node, one barrier,
// 2-MFMA phase-B per wave. Gather: pure 4-wide mult-4-padded loop (no tail),
// unroll 2 -> 8 feature + 8 dinv loads in flight; 8 blocks/CU for latency hiding.
__global__ __launch_bounds__(256, 8) void aggemm_k(const unsigned short* __restrict__ tb,
                                                   const unsigned* __restrict__ fill4,
                                                   const int2* __restrict__ ell,
                                                   const float* __restrict__ dinv,
                                                   const unsigned short* __restrict__ Wt,
                                                   const float* __restrict__ bias,
                                                   unsigned short* __restrict__ outB,
                                                   int relu) {
    __shared__ unsigned short tile[16][136];  // 272 B row stride: 4-bank row shift
    int lane16 = threadIdx.x & 15;
    int local = threadIdx.x >> 4;
    int n = blockIdx.x * 16 + local;  // 3125*16 == N_NODES exactly, no guard
    float dn = dinv[n];
#define UNP(q, f)                                                 \
    float f##0 = __uint_as_float((q).x << 16);                    \
    float f##1 = __uint_as_float((q).x & 0xffff0000u);            \
    float f##2 = __uint_as_float((q).y << 16);                    \
    float f##3 = __uint_as_float((q).y & 0xffff0000u);            \
    float f##4 = __uint_as_float((q).z << 16);                    \
    float f##5 = __uint_as_float((q).z & 0xffff0000u);            \
    float f##6 = __uint_as_float((q).w << 16);                    \
    float f##7 = __uint_as_float((q).w & 0xffff0000u);
    uint4 qs = ((const uint4*)(tb + (size_t)n * 128))[lane16];
    UNP(qs, S)
    float acc0 = S0 * dn, acc1 = S1 * dn, acc2 = S2 * dn, acc3 = S3 * dn;
    float acc4 = S4 * dn, acc5 = S5 * dn, acc6 = S6 * dn, acc7 = S7 * dn;
    unsigned f4 = fill4[n];
#pragma unroll
    for (int r = 0; r < NR; ++r) {
        int c = (f4 >> (8 * r)) & 255;  // multiple of 4 (zero-padded at build)
        const int2* ep = ell + ((size_t)n * NR + r) * PAD_R;
#pragma unroll 2
        for (int i = 0; i < c; i += 4) {
            int2 p0 = ep[i], p1 = ep[i + 1], p2 = ep[i + 2], p3 = ep[i + 3];
            uint4 q0 = ((const uint4*)(tb + (size_t)p0.x * 128))[lane16];
            uint4 q1 = ((const uint4*)(tb + (size_t)p1.x * 128))[lane16];
            uint4 q2 = ((const uint4*)(tb + (size_t)p2.x * 128))[lane16];
            uint4 q3 = ((const uint4*)(tb + (size_t)p3.x * 128))[lane16];
            float w0 = __int_as_float(p0.y) * dinv[p0.x];
            float w1 = __int_as_float(p1.y) * dinv[p1.x];
            float w2 = __int_as_float(p2.y) * dinv[p2.x];
            float w3 = __int_as_float(p3.y) * dinv[p3.x];
            UNP(q0, A)
            UNP(q1, B)
            UNP(q2, C)
            UNP(q3, D)
            acc0 += A0 * w0 + B0 * w1 + C0 * w2 + D0 * w3;
            acc1 += A1 * w0 + B1 * w1 + C1 * w2 + D1 * w3;
            acc2 += A2 * w0 + B2 * w1 + C2 * w2 + D2 * w3;
            acc3 += A3 * w0 + B3 * w1 + C3 * w2 + D3 * w3;
            acc4 += A4 * w0 + B4 * w1 + C4 * w2 + D4 * w3;
            acc5 += A5 * w0 + B5 * w1 + C5 * w2 + D5 * w3;
            acc6 += A6 * w0 + B6 * w1 + C6 * w2 + D6 * w3;
            acc7 += A7 * w0 + B7 * w1 + C7 * w2 + D7 * w3;
        }
    }
#undef UNP
    // finish aggregation (outer dn scale), round to bf16 into the LDS tile
    acc0 *= dn; acc1 *= dn; acc2 *= dn; acc3 *= dn;
    acc4 *= dn; acc5 *= dn; acc6 *= dn; acc7 *= dn;
    uint4 pk;
    pk.x = bf16rne(acc0) | (bf16rne(acc1) << 16);
    pk.y = bf16rne(acc2) | (bf16rne(acc3) << 16);
    pk.z = bf16rne(acc4) | (bf16rne(acc5) << 16);
    pk.w = bf16rne(acc6) | (bf16rne(acc7) << 16);
    *(uint4*)&tile[local][lane16 * 8] = pk;
    __syncthreads();

    // Phase B: C[16][128] = tile @ W; wave w owns output cols [w*32, w*32+32)
    int wave = threadIdx.x >> 6;
    int lane = threadIdx.x & 63;
    int m = lane & 15;
    int quad = lane >> 4;
    f32x4 acc[2] = {};
#pragma unroll
    for (int kc = 0; kc < 4; ++kc) {
        bf16x8 a = *(const bf16x8*)&tile[m][kc * 32 + quad * 8];
#pragma unroll
        for (int ctl = 0; ctl < 2; ++ctl) {
            int ct = wave * 2 + ctl;
            bf16x8 bfr = *(const bf16x8*)(Wt + (size_t)(ct * 16 + m) * 128 + kc * 32 + quad * 8);
            acc[ctl] = __builtin_amdgcn_mfma_f32_16x16x32_bf16(a, bfr, acc[ctl], 0, 0, 0);
        }
    }
#pragma unroll
    for (int ctl = 0; ctl < 2; ++ctl) {
        int col = (wave * 2 + ctl) * 16 + m;
        float bv = bias[col];
#pragma unroll
        for (int r = 0; r < 4; ++r) {
            int nr = blockIdx.x * 16 + quad * 4 + r;
            float v = acc[ctl][r] + bv;
            if (relu) v = fmaxf(v, 0.f);
            outB[(size_t)nr * 128 + col] = (unsigned short)bf16rne(v);
        }
    }
}

// ---------------- pooling stage 1: run-length partial sums over sorted batch -------
#define PCHUNK 49
__global__ __launch_bounds__(128) void pool1_k(const unsigned short* __restrict__ hb,
                                               const int* __restrict__ batch,
                                               float* __restrict__ pool) {
    int c = threadIdx.x;
    int n0 = blockIdx.x * PCHUNK;
    if (n0 >= N_NODES) return;
    int n1 = n0 + PCHUNK;
    if (n1 > N_NODES) n1 = N_NODES;
    int g = batch[n0];
    float run = 0.f;
    for (int n = n0; n < n1; ++n) {
        int gn = batch[n];
        if (gn != g) {
            atomicAdd(&pool[g * 128 + c], run);
            run = 0.f;
            g = gn;
        }
        run += __uint_as_float((unsigned)hb[(size_t)n * 128 + c] << 16);
    }
    atomicAdd(&pool[g * 128 + c], run);
}

// ---------------- classifier: emb = pool/cnt; out = (emb@lw1+lb1)@lw2+lb2 ----------
__global__ __launch_bounds__(128) void cls2_k(const float* __restrict__ pool,
                                              const int* __restrict__ gstart,
                                              const float* __restrict__ lw1,
                                              const float* __restrict__ lb1,
                                              const float* __restrict__ lw2,
                                              const float* __restrict__ lb2,
                                              float* __restrict__ out) {
    __shared__ float emb[128];
    __shared__ float mid[128];
    int g = blockIdx.x, c = threadIdx.x;
    float cntf = fmaxf((float)(gstart[g + 1] - gstart[g]), 1.0f);
    emb[c] = pool[(size_t)g * 128 + c] / cntf;
    __syncthreads();
    float a = lb1[c];
    for (int k = 0; k < 128; ++k) a += emb[k] * lw1[k * 128 + c];
    mid[c] = a;
    __syncthreads();
    if (c < OUT_CH) {
        float o = lb2[c];
        for (int k = 0; k < 128; ++k) o += mid[k] * lw2[k * OUT_CH + c];
        out[g * OUT_CH + c] = o;
    }
}

extern "C" void kernel_launch(void* const* d_in, const int* in_sizes, int n_in,
                              void* d_out, int out_size, void* d_ws, size_t ws_size,
                              hipStream_t stream) {
    const float* x = (const float*)d_in[0];
    const int* ei = (const int*)d_in[1];
    const int* src = ei;
    const int* dst = ei + N_EDGES;
    const float* ew = (const float*)d_in[2];
    const int* batch = (const int*)d_in[3];
    const float* W1 = (const float*)d_in[4];
    const float* b1 = (const float*)d_in[5];
    const float* W2 = (const float*)d_in[6];
    const float* b2 = (const float*)d_in[7];
    const float* W3 = (const float*)d_in[8];
    const float* b3 = (const float*)d_in[9];
    const float* lw1 = (const float*)d_in[10];
    const float* lb1 = (const float*)d_in[11];
    const float* lw2 = (const float*)d_in[12];
    const float* lb2 = (const float*)d_in[13];
    float* out = (float*)d_out;

    char* ws = (char*)d_ws;
    size_t off = 0;
    auto alloc = [&](size_t bytes) {
        size_t cur = off;
        off += (bytes + 255) & ~(size_t)255;
        return cur;
    };
    // zero-init region (one memset): bucket counters + pool sums
    size_t o_bcount = alloc(NBUCK * 4);
    size_t o_pool = alloc(N_GRAPHS * HID * 4);
    size_t zero_end = off;
    // rest
    size_t o_fill4 = alloc(N_NODES * 4);
    size_t o_dinv = alloc(N_NODES * 4);
    size_t o_gstart = alloc((N_GRAPHS + 1) * 4);
    size_t o_wt = alloc(3 * 16384 * 2);
    size_t o_ell = alloc((size_t)N_NODES * NR * PAD_R * 8);
    size_t o_cpair = alloc((size_t)NBUCK * BCAP * 8);
    size_t o_featA = alloc((size_t)N_NODES * HID * 2);  // feature ping (bf16)
    size_t o_featB = alloc((size_t)N_NODES * HID * 2);  // feature pong (bf16)
    (void)ws_size;

    int* bcount = (int*)(ws + o_bcount);
    float* pool = (float*)(ws + o_pool);
    unsigned* fill4 = (unsigned*)(ws + o_fill4);
    float* dinv = (float*)(ws + o_dinv);
    int* gstart = (int*)(ws + o_gstart);
    unsigned short* Wt = (unsigned short*)(ws + o_wt);
    int2* ell = (int2*)(ws + o_ell);
    int2* cpair = (int2*)(ws + o_cpair);
    unsigned short* featA = (unsigned short*)(ws + o_featA);
    unsigned short* featB = (unsigned short*)(ws + o_featB);

    hipMemsetAsync(d_ws, 0, zero_end, stream);

    // two-phase ELL build (line-aligned reservations, src-range-bucketed rows)
    bucket_k<<<P1BLK, 1024, 0, stream>>>(src, dst, ew, bcount, cpair);
    ell_scatter_k<<<NBUCK, 512, 0, stream>>>(bcount, cpair, ell, fill4, dinv);
    prep_k<<<196, 256, 0, stream>>>(batch, gstart, W1, W2, W3, Wt);
    xconv_k<<<(N_NODES * 16 + 255) / 256, 256, 0, stream>>>(x, featA);

    int agg_blocks = (N_NODES + 15) / 16;  // 3125, *16 == N_NODES exactly
    // fused layers: out = relu?( agg(feat) @ W + b )
    aggemm_k<<<agg_blocks, 256, 0, stream>>>(featA, fill4, ell, dinv, Wt, b1, featB, 1);
    aggemm_k<<<agg_blocks, 256, 0, stream>>>(featB, fill4, ell, dinv, Wt + 16384, b2, featA, 1);
    aggemm_k<<<agg_blocks, 256, 0, stream>>>(featA, fill4, ell, dinv, Wt + 32768, b3, featB, 0);

    // two-stage mean-pool (bf16 in) + classify
    pool1_k<<<(N_NODES + PCHUNK - 1) / PCHUNK, 128, 0, stream>>>(featB, batch, pool);
    cls2_k<<<N_GRAPHS, 128, 0, stream>>>(pool, gstart, lw1, lb1, lw2, lb2, out);
}

// Round 7
// 354.475 us; speedup vs baseline: 2.0140x; 1.1638x over previous
//
#include <hip/hip_runtime.h>

#define N_NODES 50000
#define N_EDGES 1600000
#define N_GRAPHS 256
#define HID 128
#define OUT_CH 10
#define NBUCK 512    // dst buckets for two-phase build
#define BNODES ((N_NODES + NBUCK - 1) / NBUCK)  // 98 nodes per bucket
#define BCAP 6144    // slots per bucket region
#define P1BLK 250    // phase-1 blocks (EPB = 6400, divisible by 4)
#define EPB (N_EDGES / P1BLK)
#define DSENTINEL 127  // dloc sentinel for alignment-pad slots (valid dloc < 98)
#define NR 4           // src ranges for L2-windowed gather
#define RSTEP ((N_NODES + NR - 1) / NR)  // 12500 -> 3.2 MB feature window / range
#define PAD_R 40       // slots per (node, range); global max deg <80, per-range max ~30

typedef __bf16 bf16x8 __attribute__((ext_vector_type(8)));
typedef float f32x4 __attribute__((ext_vector_type(4)));

__device__ inline unsigned bf16rne(float f) {
    unsigned u = __float_as_uint(f);
    return (u + 0x7fffu + ((u >> 16) & 1u)) >> 16;
}

// cpair payload: .x = (dloc<<16) | src   (src < 65536, dloc < 98), .y = bitcast w
// ---------------- phase 1: bucket edges, line-aligned per-block reservations -------
__global__ __launch_bounds__(1024) void bucket_k(const int* __restrict__ src,
                                                 const int* __restrict__ dst,
                                                 const float* __restrict__ ew,
                                                 int* __restrict__ bcount,
                                                 int2* __restrict__ cpair) {
    __shared__ int hist[NBUCK];
    __shared__ int base[NBUCK];
    int t = threadIdx.x;
    for (int i = t; i < NBUCK; i += 1024) hist[i] = 0;
    __syncthreads();
    const int ch0 = blockIdx.x * (EPB / 4);
    const int ch1 = ch0 + (EPB / 4);
    const int4* dst4 = (const int4*)dst;
    for (int ci = ch0 + t; ci < ch1; ci += 1024) {
        int4 d4 = dst4[ci];
        atomicAdd(&hist[d4.x / BNODES], 1);
        atomicAdd(&hist[d4.y / BNODES], 1);
        atomicAdd(&hist[d4.z / BNODES], 1);
        atomicAdd(&hist[d4.w / BNODES], 1);
    }
    __syncthreads();
    // reserve line-aligned ranges (8 slots = 64 B): every cpair line owned by ONE block
    for (int i = t; i < NBUCK; i += 1024) {
        int c = hist[i];
        base[i] = (c > 0) ? atomicAdd(&bcount[i], (c + 7) & ~7) : 0;
        hist[i] = 0;  // reuse as within-reservation cursor
    }
    __syncthreads();
    for (int ci = ch0 + t; ci < ch1; ci += 1024) {
        int4 d4 = dst4[ci];
        int e = ci * 4;
#define PROC(dd, ee)                                              \
        {                                                         \
            int b = (dd) / BNODES;                                \
            int off = base[b] + atomicAdd(&hist[b], 1);           \
            if (off < BCAP) {                                     \
                int2 p;                                           \
                p.x = (((dd) - b * BNODES) << 16) | src[ee];      \
                p.y = __float_as_int(ew[ee]);                     \
                cpair[b * BCAP + off] = p;                        \
            }                                                     \
        }
        PROC(d4.x, e)
        PROC(d4.y, e + 1)
        PROC(d4.z, e + 2)
        PROC(d4.w, e + 3)
#undef PROC
    }
    __syncthreads();
    // pad slack slots [c, align8(c)) with sentinel so phase 2 can skip them
    for (int i = t; i < NBUCK; i += 1024) {
        int c = hist[i];
        int ac = (c + 7) & ~7;
        for (int j = c; j < ac; ++j) {
            int off = base[i] + j;
            if (off < BCAP) {
                int2 p;
                p.x = DSENTINEL << 16;
                p.y = 0;
                cpair[i * BCAP + off] = p;
            }
        }
    }
}

// ---------------- phase 2: bucket -> src-range-bucketed ELL + fill4 + dinv ---------
// ELL layout: [n][r][PAD_R]; fill4[n] = packed uchar4 counts ROUNDED UP to mult-4;
// slots [c, round4(c)) are zero entries (src=0, w=0) so the gather loop has no tail.
__global__ __launch_bounds__(512) void ell_scatter_k(const int* __restrict__ bcount,
                                                     const int2* __restrict__ cpair,
                                                     int2* __restrict__ ell,
                                                     unsigned* __restrict__ fill4,
                                                     float* __restrict__ dinv) {
    __shared__ int lfill[BNODES * NR];
    __shared__ float wsum[BNODES];
    int b = blockIdx.x;
    int t = threadIdx.x;
    for (int i = t; i < BNODES * NR; i += 512) lfill[i] = 0;
    for (int i = t; i < BNODES; i += 512) wsum[i] = 0.f;
    __syncthreads();
    int cnt = bcount[b];
    if (cnt > BCAP) cnt = BCAP;
    int n0 = b * BNODES;
    int sbase = b * BCAP;
    for (int i = t; i < cnt; i += 512) {
        int2 p = cpair[sbase + i];
        int dloc = p.x >> 16;
        if (dloc < BNODES) {
            int s = p.x & 0xffff;
            int r = s / RSTEP;
            int pos = atomicAdd(&lfill[dloc * NR + r], 1);
            atomicAdd(&wsum[dloc], __int_as_float(p.y));
            if (pos < PAD_R) {
                int2 q;
                q.x = s;
                q.y = p.y;
                ell[((size_t)(n0 + dloc) * NR + r) * PAD_R + pos] = q;
            }
        }
    }
    __syncthreads();
    for (int i = t; i < BNODES; i += 512) {
        int n = n0 + i;
        if (n < N_NODES) {
            unsigned f = 0;
            int2 z; z.x = 0; z.y = 0;
#pragma unroll
            for (int r = 0; r < NR; ++r) {
                int c = lfill[i * NR + r];
                if (c > PAD_R) c = PAD_R;
                int cp = (c + 3) & ~3;           // mult-4 (<= PAD_R since PAD_R%4==0)
                for (int j = c; j < cp; ++j)      // zero-pad: w=0 contributes nothing
                    ell[((size_t)n * NR + r) * PAD_R + j] = z;
                f |= (unsigned)cp << (8 * r);
            }
            fill4[n] = f;
            dinv[n] = rsqrtf(wsum[i] + 1.0f);
        }
    }
}

// ---------------- fused prep: graph boundaries + W bf16 transpose ------------------
__global__ __launch_bounds__(256) void prep_k(const int* __restrict__ batch,
                                              int* __restrict__ gstart,
                                              const float* __restrict__ W1,
                                              const float* __restrict__ W2,
                                              const float* __restrict__ W3,
                                              unsigned short* __restrict__ Wt) {
    int idx = blockIdx.x * 256 + threadIdx.x;
    if (idx < 3 * 16384) {
        int m = idx >> 14;
        int r = idx & 16383;
        const float* W = (m == 0) ? W1 : (m == 1) ? W2 : W3;
        int c = r >> 7, k = r & 127;
        Wt[idx] = (unsigned short)bf16rne(W[k * 128 + c]);
    }
    if (idx < N_NODES) {
        int b = batch[idx];
        int bprev = (idx == 0) ? -1 : batch[idx - 1];
        for (int g = bprev + 1; g <= b; ++g) gstart[g] = idx;
        if (idx == N_NODES - 1) {
            for (int g = b + 1; g <= N_GRAPHS; ++g) gstart[g] = N_NODES;
        }
    }
}

// ---------------- one-time x fp32 -> bf16 convert (layer-1 gather table) -----------
__global__ __launch_bounds__(256) void xconv_k(const float* __restrict__ x,
                                               unsigned short* __restrict__ xb) {
    int i = blockIdx.x * 256 + threadIdx.x;  // one thread per 8 channels
    if (i >= N_NODES * 16) return;
    const float4* p = (const float4*)x + (size_t)i * 2;
    float4 lo = p[0], hi = p[1];
    uint4 pk;
    pk.x = bf16rne(lo.x) | (bf16rne(lo.y) << 16);
    pk.y = bf16rne(lo.z) | (bf16rne(lo.w) << 16);
    pk.z = bf16rne(hi.x) | (bf16rne(hi.y) << 16);
    pk.w = bf16rne(hi.z) | (bf16rne(hi.w) << 16);
    ((uint4*)xb)[i] = pk;
}

// ---------------- fused layer: out = relu( agg(x) @ W + b ) ------------------------
// Round-1 skeleton (measured best): 16 nodes/block, 16 lanes/node, one barrier,
// 2-MFMA phase-B per wave. Gather: pure 4-wide mult-4-padded loop (no tail),
// unroll 2 -> 8 feature + 8 dinv loads in flight. bounds (256,6): ~85 VGPR cap --
// (256,8) capped at 64 and SPILLED (round 6: WRITE_SIZE 73 MB of scratch traffic).
__global__ __launch_bounds__(256, 6) void aggemm_k(const unsigned short* __restrict__ tb,
                                                   const unsigned* __restrict__ fill4,
                                                   const int2* __restrict__ ell,
                                                   const float* __restrict__ dinv,
                                                   const unsigned short* __restrict__ Wt,
                                                   const float* __restrict__ bias,
                                                   unsigned short* __restrict__ outB,
                                                   int relu) {
    __shared__ unsigned short tile[16][136];  // 272 B row stride: 4-bank row shift
    int lane16 = threadIdx.x & 15;
    int local = threadIdx.x >> 4;
    int n = blockIdx.x * 16 + local;  // 3125*16 == N_NODES exactly, no guard
    float dn = dinv[n];
#define UNP(q, f)                                                 \
    float f##0 = __uint_as_float((q).x << 16);                    \
    float f##1 = __uint_as_float((q).x & 0xffff0000u);            \
    float f##2 = __uint_as_float((q).y << 16);                    \
    float f##3 = __uint_as_float((q).y & 0xffff0000u);            \
    float f##4 = __uint_as_float((q).z << 16);                    \
    float f##5 = __uint_as_float((q).z & 0xffff0000u);            \
    float f##6 = __uint_as_float((q).w << 16);                    \
    float f##7 = __uint_as_float((q).w & 0xffff0000u);
    uint4 qs = ((const uint4*)(tb + (size_t)n * 128))[lane16];
    UNP(qs, S)
    float acc0 = S0 * dn, acc1 = S1 * dn, acc2 = S2 * dn, acc3 = S3 * dn;
    float acc4 = S4 * dn, acc5 = S5 * dn, acc6 = S6 * dn, acc7 = S7 * dn;
    unsigned f4 = fill4[n];
#pragma unroll
    for (int r = 0; r < NR; ++r) {
        int c = (f4 >> (8 * r)) & 255;  // multiple of 4 (zero-padded at build)
        const int2* ep = ell + ((size_t)n * NR + r) * PAD_R;
#pragma unroll 2
        for (int i = 0; i < c; i += 4) {
            int2 p0 = ep[i], p1 = ep[i + 1], p2 = ep[i + 2], p3 = ep[i + 3];
            uint4 q0 = ((const uint4*)(tb + (size_t)p0.x * 128))[lane16];
            uint4 q1 = ((const uint4*)(tb + (size_t)p1.x * 128))[lane16];
            uint4 q2 = ((const uint4*)(tb + (size_t)p2.x * 128))[lane16];
            uint4 q3 = ((const uint4*)(tb + (size_t)p3.x * 128))[lane16];
            float w0 = __int_as_float(p0.y) * dinv[p0.x];
            float w1 = __int_as_float(p1.y) * dinv[p1.x];
            float w2 = __int_as_float(p2.y) * dinv[p2.x];
            float w3 = __int_as_float(p3.y) * dinv[p3.x];
            UNP(q0, A)
            UNP(q1, B)
            UNP(q2, C)
            UNP(q3, D)
            acc0 += A0 * w0 + B0 * w1 + C0 * w2 + D0 * w3;
            acc1 += A1 * w0 + B1 * w1 + C1 * w2 + D1 * w3;
            acc2 += A2 * w0 + B2 * w1 + C2 * w2 + D2 * w3;
            acc3 += A3 * w0 + B3 * w1 + C3 * w2 + D3 * w3;
            acc4 += A4 * w0 + B4 * w1 + C4 * w2 + D4 * w3;
            acc5 += A5 * w0 + B5 * w1 + C5 * w2 + D5 * w3;
            acc6 += A6 * w0 + B6 * w1 + C6 * w2 + D6 * w3;
            acc7 += A7 * w0 + B7 * w1 + C7 * w2 + D7 * w3;
        }
    }
#undef UNP
    // finish aggregation (outer dn scale), round to bf16 into the LDS tile
    acc0 *= dn; acc1 *= dn; acc2 *= dn; acc3 *= dn;
    acc4 *= dn; acc5 *= dn; acc6 *= dn; acc7 *= dn;
    uint4 pk;
    pk.x = bf16rne(acc0) | (bf16rne(acc1) << 16);
    pk.y = bf16rne(acc2) | (bf16rne(acc3) << 16);
    pk.z = bf16rne(acc4) | (bf16rne(acc5) << 16);
    pk.w = bf16rne(acc6) | (bf16rne(acc7) << 16);
    *(uint4*)&tile[local][lane16 * 8] = pk;
    __syncthreads();

    // Phase B: C[16][128] = tile @ W; wave w owns output cols [w*32, w*32+32)
    int wave = threadIdx.x >> 6;
    int lane = threadIdx.x & 63;
    int m = lane & 15;
    int quad = lane >> 4;
    f32x4 acc[2] = {};
#pragma unroll
    for (int kc = 0; kc < 4; ++kc) {
        bf16x8 a = *(const bf16x8*)&tile[m][kc * 32 + quad * 8];
#pragma unroll
        for (int ctl = 0; ctl < 2; ++ctl) {
            int ct = wave * 2 + ctl;
            bf16x8 bfr = *(const bf16x8*)(Wt + (size_t)(ct * 16 + m) * 128 + kc * 32 + quad * 8);
            acc[ctl] = __builtin_amdgcn_mfma_f32_16x16x32_bf16(a, bfr, acc[ctl], 0, 0, 0);
        }
    }
#pragma unroll
    for (int ctl = 0; ctl < 2; ++ctl) {
        int col = (wave * 2 + ctl) * 16 + m;
        float bv = bias[col];
#pragma unroll
        for (int r = 0; r < 4; ++r) {
            int nr = blockIdx.x * 16 + quad * 4 + r;
            float v = acc[ctl][r] + bv;
            if (relu) v = fmaxf(v, 0.f);
            outB[(size_t)nr * 128 + col] = (unsigned short)bf16rne(v);
        }
    }
}

// ---------------- pooling stage 1: run-length partial sums over sorted batch -------
#define PCHUNK 49
__global__ __launch_bounds__(128) void pool1_k(const unsigned short* __restrict__ hb,
                                               const int* __restrict__ batch,
                                               float* __restrict__ pool) {
    int c = threadIdx.x;
    int n0 = blockIdx.x * PCHUNK;
    if (n0 >= N_NODES) return;
    int n1 = n0 + PCHUNK;
    if (n1 > N_NODES) n1 = N_NODES;
    int g = batch[n0];
    float run = 0.f;
    for (int n = n0; n < n1; ++n) {
        int gn = batch[n];
        if (gn != g) {
            atomicAdd(&pool[g * 128 + c], run);
            run = 0.f;
            g = gn;
        }
        run += __uint_as_float((unsigned)hb[(size_t)n * 128 + c] << 16);
    }
    atomicAdd(&pool[g * 128 + c], run);
}

// ---------------- classifier: emb = pool/cnt; out = (emb@lw1+lb1)@lw2+lb2 ----------
__global__ __launch_bounds__(128) void cls2_k(const float* __restrict__ pool,
                                              const int* __restrict__ gstart,
                                              const float* __restrict__ lw1,
                                              const float* __restrict__ lb1,
                                              const float* __restrict__ lw2,
                                              const float* __restrict__ lb2,
                                              float* __restrict__ out) {
    __shared__ float emb[128];
    __shared__ float mid[128];
    int g = blockIdx.x, c = threadIdx.x;
    float cntf = fmaxf((float)(gstart[g + 1] - gstart[g]), 1.0f);
    emb[c] = pool[(size_t)g * 128 + c] / cntf;
    __syncthreads();
    float a = lb1[c];
    for (int k = 0; k < 128; ++k) a += emb[k] * lw1[k * 128 + c];
    mid[c] = a;
    __syncthreads();
    if (c < OUT_CH) {
        float o = lb2[c];
        for (int k = 0; k < 128; ++k) o += mid[k] * lw2[k * OUT_CH + c];
        out[g * OUT_CH + c] = o;
    }
}

extern "C" void kernel_launch(void* const* d_in, const int* in_sizes, int n_in,
                              void* d_out, int out_size, void* d_ws, size_t ws_size,
                              hipStream_t stream) {
    const float* x = (const float*)d_in[0];
    const int* ei = (const int*)d_in[1];
    const int* src = ei;
    const int* dst = ei + N_EDGES;
    const float* ew = (const float*)d_in[2];
    const int* batch = (const int*)d_in[3];
    const float* W1 = (const float*)d_in[4];
    const float* b1 = (const float*)d_in[5];
    const float* W2 = (const float*)d_in[6];
    const float* b2 = (const float*)d_in[7];
    const float* W3 = (const float*)d_in[8];
    const float* b3 = (const float*)d_in[9];
    const float* lw1 = (const float*)d_in[10];
    const float* lb1 = (const float*)d_in[11];
    const float* lw2 = (const float*)d_in[12];
    const float* lb2 = (const float*)d_in[13];
    float* out = (float*)d_out;

    char* ws = (char*)d_ws;
    size_t off = 0;
    auto alloc = [&](size_t bytes) {
        size_t cur = off;
        off += (bytes + 255) & ~(size_t)255;
        return cur;
    };
    // zero-init region (one memset): bucket counters + pool sums
    size_t o_bcount = alloc(NBUCK * 4);
    size_t o_pool = alloc(N_GRAPHS * HID * 4);
    size_t zero_end = off;
    // rest
    size_t o_fill4 = alloc(N_NODES * 4);
    size_t o_dinv = alloc(N_NODES * 4);
    size_t o_gstart = alloc((N_GRAPHS + 1) * 4);
    size_t o_wt = alloc(3 * 16384 * 2);
    size_t o_ell = alloc((size_t)N_NODES * NR * PAD_R * 8);
    size_t o_cpair = alloc((size_t)NBUCK * BCAP * 8);
    size_t o_featA = alloc((size_t)N_NODES * HID * 2);  // feature ping (bf16)
    size_t o_featB = alloc((size_t)N_NODES * HID * 2);  // feature pong (bf16)
    (void)ws_size;

    int* bcount = (int*)(ws + o_bcount);
    float* pool = (float*)(ws + o_pool);
    unsigned* fill4 = (unsigned*)(ws + o_fill4);
    float* dinv = (float*)(ws + o_dinv);
    int* gstart = (int*)(ws + o_gstart);
    unsigned short* Wt = (unsigned short*)(ws + o_wt);
    int2* ell = (int2*)(ws + o_ell);
    int2* cpair = (int2*)(ws + o_cpair);
    unsigned short* featA = (unsigned short*)(ws + o_featA);
    unsigned short* featB = (unsigned short*)(ws + o_featB);

    hipMemsetAsync(d_ws, 0, zero_end, stream);

    // two-phase ELL build (line-aligned reservations, src-range-bucketed rows)
    bucket_k<<<P1BLK, 1024, 0, stream>>>(src, dst, ew, bcount, cpair);
    ell_scatter_k<<<NBUCK, 512, 0, stream>>>(bcount, cpair, ell, fill4, dinv);
    prep_k<<<196, 256, 0, stream>>>(batch, gstart, W1, W2, W3, Wt);
    xconv_k<<<(N_NODES * 16 + 255) / 256, 256, 0, stream>>>(x, featA);

    int agg_blocks = (N_NODES + 15) / 16;  // 3125, *16 == N_NODES exactly
    // fused layers: out = relu?( agg(feat) @ W + b )
    aggemm_k<<<agg_blocks, 256, 0, stream>>>(featA, fill4, ell, dinv, Wt, b1, featB, 1);
    aggemm_k<<<agg_blocks, 256, 0, stream>>>(featB, fill4, ell, dinv, Wt + 16384, b2, featA, 1);
    aggemm_k<<<agg_blocks, 256, 0, stream>>>(featA, fill4, ell, dinv, Wt + 32768, b3, featB, 0);

    // two-stage mean-pool (bf16 in) + classify
    pool1_k<<<(N_NODES + PCHUNK - 1) / PCHUNK, 128, 0, stream>>>(featB, batch, pool);
    cls2_k<<<N_GRAPHS, 128, 0, stream>>>(pool, gstart, lw1, lb1, lw2, lb2, out);
}